// Round 1
// baseline (767.497 us; speedup 1.0000x reference)
//
#include <hip/hip_runtime.h>

// Transformer block. fp32 in/out, bf16 MFMA internal, fp32 accumulation.
// DIM=768 HID=3072 HEADS=8 DEPTH=96 SEQ=128 GROUPS(B*F)=128 ROWS=16384
// R4: fused MFMA attention (QK^T -> softmax -> PV in one kernel per head).
// R5: + XCD-aware bijective block swizzle in gemm_kernel (T1/m204);
//     + QKV projections merged into one grid.z=3 launch (A/B/C strided).

#define NROWS 16384
#define TDIM 768
#define THID 3072
#define EPS 1e-5f

typedef short bf16x8 __attribute__((ext_vector_type(8)));
typedef float f32x4 __attribute__((ext_vector_type(4)));

__device__ __forceinline__ float b2f(unsigned short u) {
    union { unsigned int i; float f; } v; v.i = ((unsigned int)u) << 16; return v.f;
}
__device__ __forceinline__ unsigned short f2b(float f) {
    union { float f; unsigned int i; } v; v.f = f;
    unsigned int r = v.i + 0x7fffu + ((v.i >> 16) & 1u);
    return (unsigned short)(r >> 16);
}

// async 16B global -> LDS (lds dest is wave-uniform base; HW adds lane*16)
__device__ __forceinline__ void async_copy16(const unsigned short* g, unsigned short* l) {
    __builtin_amdgcn_global_load_lds(
        (const __attribute__((address_space(1))) unsigned int*)g,
        (__attribute__((address_space(3))) unsigned int*)l,
        16, 0, 0);
}

// ---------------- fp32 [K][N] -> bf16 transposed [N][K]
__global__ __launch_bounds__(256) void cvt_t_kernel(
    const float* __restrict__ src, unsigned short* __restrict__ dst, int K, int N)
{
    __shared__ unsigned short tile[32][33];
    int n0 = blockIdx.x * 32, k0 = blockIdx.y * 32;
    int tx = threadIdx.x & 31, ty = threadIdx.x >> 5;
#pragma unroll
    for (int r = ty; r < 32; r += 8)
        tile[r][tx] = f2b(src[(size_t)(k0 + r) * N + n0 + tx]);
    __syncthreads();
#pragma unroll
    for (int r = ty; r < 32; r += 8)
        dst[(size_t)(n0 + r) * K + k0 + tx] = tile[tx][r];
}

// ---------------- LayerNorm: one block per row, up to 3 tensors via blockIdx.y
template<bool IN_F32>
__global__ __launch_bounds__(256) void ln_kernel(
    const void* __restrict__ x0, const void* __restrict__ x1,
    const void* __restrict__ x2,
    const float* __restrict__ g, const float* __restrict__ bb,
    unsigned short* __restrict__ o0, unsigned short* __restrict__ o1,
    unsigned short* __restrict__ o2)
{
    int t = blockIdx.y;
    const void* x = (t == 0) ? x0 : (t == 1) ? x1 : x2;
    unsigned short* o = (t == 0) ? o0 : (t == 1) ? o1 : o2;
    size_t base = (size_t)blockIdx.x * TDIM;
    int tid = threadIdx.x;
    float v[3]; float sum = 0.f, sq = 0.f;
#pragma unroll
    for (int i = 0; i < 3; i++) {
        if constexpr (IN_F32) v[i] = ((const float*)x)[base + tid + i * 256];
        else v[i] = b2f(((const unsigned short*)x)[base + tid + i * 256]);
        sum += v[i]; sq += v[i] * v[i];
    }
#pragma unroll
    for (int o_ = 32; o_ > 0; o_ >>= 1) {
        sum += __shfl_down(sum, o_); sq += __shfl_down(sq, o_);
    }
    __shared__ float s1[4], s2[4];
    __shared__ float smu, srs;
    int wave = tid >> 6, lane = tid & 63;
    if (lane == 0) { s1[wave] = sum; s2[wave] = sq; }
    __syncthreads();
    if (tid == 0) {
        float S = s1[0] + s1[1] + s1[2] + s1[3];
        float Q = s2[0] + s2[1] + s2[2] + s2[3];
        float mu = S / (float)TDIM;
        float var = Q / (float)TDIM - mu * mu;
        smu = mu; srs = rsqrtf(var + EPS);
    }
    __syncthreads();
    float mu = smu, rs = srs;
#pragma unroll
    for (int i = 0; i < 3; i++) {
        int c = tid + i * 256;
        o[base + c] = f2b((v[i] - mu) * rs * g[c] + bb[c]);
    }
}

// ---------------- MFMA GEMM: C[M,N] = op(A[M,K] @ BT[N,K]^T (+bias)(+gelu)(+res))
// grid.z slices A/BT/C by aStride/bStride/cStride (elements) for batched QKV.
// Block mapping: XCD-aware bijective swizzle (T1, m204 formula).
template<bool BIAS, bool RES, bool GELU, bool OUTF32>
__global__ __launch_bounds__(256) void gemm_kernel(
    const unsigned short* __restrict__ A, const unsigned short* __restrict__ BT,
    const float* __restrict__ bias, const unsigned short* __restrict__ resid,
    void* __restrict__ Cv, int M, int N, int K,
    size_t aStride, size_t bStride, size_t cStride)
{
    __shared__ unsigned short sA[128][32];
    __shared__ unsigned short sB[128][32];
    int tid = threadIdx.x;

    // bijective XCD swizzle over the 2D grid
    int nbx = gridDim.x;
    int nwg = nbx * gridDim.y;
    int bid = blockIdx.y * nbx + blockIdx.x;
    int xcd = bid & 7, loc = bid >> 3;
    int qc = nwg >> 3, rc = nwg & 7;
    int swz = (xcd < rc ? xcd * (qc + 1) : rc * (qc + 1) + (xcd - rc) * qc) + loc;
    int row0 = (swz / nbx) * 128;
    int col0 = (swz % nbx) * 128;

    int z = blockIdx.z;
    A  += (size_t)z * aStride;
    BT += (size_t)z * bStride;

    int wave = tid >> 6, lane = tid & 63;
    int wm = (wave >> 1) * 64, wn = (wave & 1) * 64;
    int cl = lane & 15, quad = lane >> 4;

    f32x4 acc[4][4];
#pragma unroll
    for (int i = 0; i < 4; i++)
#pragma unroll
        for (int j = 0; j < 4; j++) acc[i][j] = (f32x4){0.f, 0.f, 0.f, 0.f};

    const unsigned short* Arow = A + (size_t)row0 * K;
    const unsigned short* Brow = BT + (size_t)col0 * K;

    for (int k0 = 0; k0 < K; k0 += 32) {
#pragma unroll
        for (int i = 0; i < 2; i++) {
            int cb = wave * 128 + i * 64;
            int c = cb + lane;
            int r = c >> 2, kc = (c & 3) << 3;
            async_copy16(Arow + (size_t)r * K + k0 + kc, &sA[0][0] + cb * 8);
            async_copy16(Brow + (size_t)r * K + k0 + kc, &sB[0][0] + cb * 8);
        }
        __syncthreads();
        bf16x8 af[4], bfr[4];
#pragma unroll
        for (int mi = 0; mi < 4; mi++)
            af[mi] = *(const bf16x8*)(&sA[wm + mi * 16 + cl][quad * 8]);
#pragma unroll
        for (int ni = 0; ni < 4; ni++)
            bfr[ni] = *(const bf16x8*)(&sB[wn + ni * 16 + cl][quad * 8]);
#pragma unroll
        for (int mi = 0; mi < 4; mi++)
#pragma unroll
            for (int ni = 0; ni < 4; ni++)
                acc[mi][ni] = __builtin_amdgcn_mfma_f32_16x16x32_bf16(
                    af[mi], bfr[ni], acc[mi][ni], 0, 0, 0);
        __syncthreads();
    }
#pragma unroll
    for (int mi = 0; mi < 4; mi++) {
#pragma unroll
        for (int ni = 0; ni < 4; ni++) {
            int gc = col0 + wn + ni * 16 + cl;
            float bv = 0.f;
            if constexpr (BIAS) bv = bias[gc];
#pragma unroll
            for (int r = 0; r < 4; r++) {
                int gr = row0 + wm + mi * 16 + quad * 4 + r;
                float v = acc[mi][ni][r];
                if constexpr (BIAS) v += bv;
                if constexpr (GELU) {
                    float x = v;
                    v = 0.5f * x * (1.0f + tanhf(0.7978845608028654f *
                            (x + 0.044715f * x * x * x)));
                }
                if constexpr (RES) v += b2f(resid[(size_t)gr * N + gc]);
                size_t idx = (size_t)gr * N + gc;
                if constexpr (OUTF32) ((float*)Cv)[idx + (size_t)z * cStride] = v;
                else ((unsigned short*)Cv)[idx + (size_t)z * cStride] = f2b(v);
            }
        }
    }
}

// ---------------- Fused attention: per-head QK^T -> softmax -> att + PV
// Block = 256 threads (4 waves), grid = 1024 heads.
// Phase1: S(128x128) via MFMA, wave quadrants 64x64.
// Softmax: register rows + 16-lane shfl + LDS exchange across wave pair.
// Phase2: O = P(128x128) @ V(128x96) via MFMA, wave = 32 rows x 96 cols.
__global__ __launch_bounds__(256) void attn_fused_kernel(
    const unsigned short* __restrict__ qh, const unsigned short* __restrict__ kh,
    const unsigned short* __restrict__ vh, float* __restrict__ att,
    unsigned short* __restrict__ attout)
{
    __shared__ __align__(16) unsigned short smem[30464];
    __shared__ float wmax[2][128];
    __shared__ float wsum[2][128];
    __shared__ float sInv[128];
    // phase1 aliases: sQ = smem[0..12287] [128][96], sK = smem[12288..] [128][96]
    // phase2 aliases: sP = smem[0..17407] [128][136], sVt = smem[17408..] [96][136]
    unsigned short* sQ = smem;
    unsigned short* sK = smem + 12288;
    unsigned short* sP = smem;
    unsigned short* sVt = smem + 17408;

    int hb = blockIdx.x, g = hb >> 3, h = hb & 7;
    int tid = threadIdx.x;
    int wave = tid >> 6, lane = tid & 63;
    int cl = lane & 15, quad = lane >> 4;
    int wm = (wave >> 1) * 64, wn = (wave & 1) * 64;

    size_t rbase = (size_t)g * 128 * TDIM + (size_t)h * 96;

    // ---- stage Q,K: 1536 16B-chunks each; chunk c -> LDS offset c*16B (linear)
#pragma unroll
    for (int it = 0; it < 6; it++) {
        int cb = wave * 384 + it * 64;
        int c = cb + lane;
        int r = c / 12, dc = (c % 12) * 8;
        async_copy16(qh + rbase + (size_t)r * TDIM + dc, sQ + (size_t)cb * 8);
        async_copy16(kh + rbase + (size_t)r * TDIM + dc, sK + (size_t)cb * 8);
    }
    __syncthreads();

    // ---- Phase 1: S = Q @ K^T (wave quadrant 64x64), K-dim 96 = 3 steps
    f32x4 acc[4][4];
#pragma unroll
    for (int i = 0; i < 4; i++)
#pragma unroll
        for (int j = 0; j < 4; j++) acc[i][j] = (f32x4){0.f, 0.f, 0.f, 0.f};
#pragma unroll
    for (int kk = 0; kk < 3; kk++) {
        bf16x8 af[4], bfr[4];
#pragma unroll
        for (int mi = 0; mi < 4; mi++)
            af[mi] = *(const bf16x8*)(sQ + (size_t)(wm + mi * 16 + cl) * 96 + kk * 32 + quad * 8);
#pragma unroll
        for (int ni = 0; ni < 4; ni++)
            bfr[ni] = *(const bf16x8*)(sK + (size_t)(wn + ni * 16 + cl) * 96 + kk * 32 + quad * 8);
#pragma unroll
        for (int mi = 0; mi < 4; mi++)
#pragma unroll
            for (int ni = 0; ni < 4; ni++)
                acc[mi][ni] = __builtin_amdgcn_mfma_f32_16x16x32_bf16(
                    af[mi], bfr[ni], acc[mi][ni], 0, 0, 0);
    }

    // ---- scale + row max (C layout: col=cl, row=quad*4+r within frag)
    const float scale = 0.10206207261596575f;  // 96^-0.5
#pragma unroll
    for (int mi = 0; mi < 4; mi++)
#pragma unroll
        for (int ni = 0; ni < 4; ni++)
#pragma unroll
            for (int r = 0; r < 4; r++) acc[mi][ni][r] *= scale;
#pragma unroll
    for (int mi = 0; mi < 4; mi++) {
#pragma unroll
        for (int r = 0; r < 4; r++) {
            float m = fmaxf(fmaxf(acc[mi][0][r], acc[mi][1][r]),
                            fmaxf(acc[mi][2][r], acc[mi][3][r]));
            m = fmaxf(m, __shfl_xor(m, 1));
            m = fmaxf(m, __shfl_xor(m, 2));
            m = fmaxf(m, __shfl_xor(m, 4));
            m = fmaxf(m, __shfl_xor(m, 8));
            if (cl == 0) wmax[wn >> 6][wm + mi * 16 + quad * 4 + r] = m;
        }
    }
    __syncthreads();  // b1: wmax ready; sQ/sK dead from here

    // ---- stage V^T into sVt[96][136] (staggered j to spread banks)
    for (int c = tid; c < 1536; c += 256) {
        int kk2 = c / 12, dc2 = (c % 12) * 8;
        uint4 t_ = *(const uint4*)(vh + rbase + (size_t)kk2 * TDIM + dc2);
        unsigned short* tp = (unsigned short*)&t_;
#pragma unroll
        for (int j = 0; j < 8; j++) {
            int jj = (j + tid) & 7;
            sVt[(size_t)(dc2 + jj) * 136 + kk2] = tp[jj];
        }
    }

    // ---- exp (unnormalized), row sum, write P(bf16) to sP
#pragma unroll
    for (int mi = 0; mi < 4; mi++) {
#pragma unroll
        for (int r = 0; r < 4; r++) {
            int row = wm + mi * 16 + quad * 4 + r;
            float rm = fmaxf(wmax[0][row], wmax[1][row]);
            float s = 0.f;
#pragma unroll
            for (int ni = 0; ni < 4; ni++) {
                float e = __expf(acc[mi][ni][r] - rm);
                acc[mi][ni][r] = e;
                s += e;
            }
            s += __shfl_xor(s, 1);
            s += __shfl_xor(s, 2);
            s += __shfl_xor(s, 4);
            s += __shfl_xor(s, 8);
            if (cl == 0) wsum[wn >> 6][row] = s;
#pragma unroll
            for (int ni = 0; ni < 4; ni++)
                sP[(size_t)row * 136 + wn + ni * 16 + cl] = f2b(acc[mi][ni][r]);
        }
    }
    __syncthreads();  // b2: wsum, sP, sVt ready

    if (tid < 128) sInv[tid] = 1.0f / (wsum[0][tid] + wsum[1][tid]);
    __syncthreads();  // b3: sInv ready

    // ---- write normalized att (fp32 output 1)
    size_t pbase = (size_t)hb * 128 * 128;
#pragma unroll
    for (int mi = 0; mi < 4; mi++) {
#pragma unroll
        for (int r = 0; r < 4; r++) {
            int row = wm + mi * 16 + quad * 4 + r;
            float iv = sInv[row];
#pragma unroll
            for (int ni = 0; ni < 4; ni++)
                att[pbase + (size_t)row * 128 + wn + ni * 16 + cl] =
                    acc[mi][ni][r] * iv;
        }
    }

    // ---- Phase 2: O = P @ V  (wave = rows [wave*32, wave*32+32), cols 0..95)
    int wm2 = wave * 32;
    f32x4 acc2[2][6];
#pragma unroll
    for (int i = 0; i < 2; i++)
#pragma unroll
        for (int j = 0; j < 6; j++) acc2[i][j] = (f32x4){0.f, 0.f, 0.f, 0.f};
#pragma unroll
    for (int ks = 0; ks < 4; ks++) {
        bf16x8 pa[2], vb[6];
#pragma unroll
        for (int mi2 = 0; mi2 < 2; mi2++)
            pa[mi2] = *(const bf16x8*)(sP + (size_t)(wm2 + mi2 * 16 + cl) * 136 + ks * 32 + quad * 8);
#pragma unroll
        for (int ni2 = 0; ni2 < 6; ni2++)
            vb[ni2] = *(const bf16x8*)(sVt + (size_t)(ni2 * 16 + cl) * 136 + ks * 32 + quad * 8);
#pragma unroll
        for (int mi2 = 0; mi2 < 2; mi2++)
#pragma unroll
            for (int ni2 = 0; ni2 < 6; ni2++)
                acc2[mi2][ni2] = __builtin_amdgcn_mfma_f32_16x16x32_bf16(
                    pa[mi2], vb[ni2], acc2[mi2][ni2], 0, 0, 0);
    }
    // epilogue: attout[row][h*96 + d] = O * inv[row]
#pragma unroll
    for (int mi2 = 0; mi2 < 2; mi2++) {
#pragma unroll
        for (int r = 0; r < 4; r++) {
            int row = wm2 + mi2 * 16 + quad * 4 + r;
            float iv = sInv[row];
#pragma unroll
            for (int ni2 = 0; ni2 < 6; ni2++) {
                int d = ni2 * 16 + cl;
                attout[rbase + (size_t)row * TDIM + d] =
                    f2b(acc2[mi2][ni2][r] * iv);
            }
        }
    }
}

extern "C" void kernel_launch(void* const* d_in, const int* in_sizes, int n_in,
                              void* d_out, int out_size, void* d_ws, size_t ws_size,
                              hipStream_t stream)
{
    const float* q     = (const float*)d_in[0];
    const float* k     = (const float*)d_in[1];
    const float* v     = (const float*)d_in[2];
    const float* ln1_g = (const float*)d_in[3];
    const float* ln1_b = (const float*)d_in[4];
    const float* wq    = (const float*)d_in[5];
    const float* wk    = (const float*)d_in[6];
    const float* wv    = (const float*)d_in[7];
    const float* wo    = (const float*)d_in[8];
    const float* wo_b  = (const float*)d_in[9];
    const float* ln2_g = (const float*)d_in[10];
    const float* ln2_b = (const float*)d_in[11];
    const float* w1    = (const float*)d_in[12];
    const float* b1    = (const float*)d_in[13];
    const float* w2    = (const float*)d_in[14];
    const float* b2    = (const float*)d_in[15];

    float* out0 = (float*)d_out;
    const size_t S = (size_t)NROWS * TDIM;  // 12,582,912
    float* att = out0 + S;                  // output 1: (2,64,8,128,128) fp32
    unsigned short* ws = (unsigned short*)d_ws;
    if (ws_size < 7 * S * sizeof(unsigned short)) return;  // need ~168 MB

    const size_t W = (size_t)TDIM * TDIM;   // 589,824
    const size_t W2 = (size_t)TDIM * THID;  // 2,359,296

    unsigned short* qn     = ws;          // slot0; later ln2y
    unsigned short* kn     = ws + S;      // slot1; later attout, then w1T/w2T
    unsigned short* vn     = ws + 2 * S;  // slot2; later y
    unsigned short* qh     = ws + 3 * S;  // slot3..5: qh/kh/vh; later hbuf (3..6)
    unsigned short* wqkvoT = ws + 6 * S;  // slot6: wq/wk/wv/wo ^T bf16 (dead at ffn1)
    unsigned short* attout = ws + S;
    unsigned short* y      = ws + 2 * S;
    unsigned short* ln2y   = ws;
    unsigned short* w1T    = ws + S;      // [3072][768], after attout dead
    unsigned short* w2T    = ws + S + W2; // [768][3072]
    unsigned short* hbuf   = ws + 3 * S;  // 16384 x 3072 (4S)

    dim3 blk(256);
    cvt_t_kernel<<<dim3(24, 24), blk, 0, stream>>>(wq, wqkvoT + 0 * W, TDIM, TDIM);
    cvt_t_kernel<<<dim3(24, 24), blk, 0, stream>>>(wk, wqkvoT + 1 * W, TDIM, TDIM);
    cvt_t_kernel<<<dim3(24, 24), blk, 0, stream>>>(wv, wqkvoT + 2 * W, TDIM, TDIM);
    cvt_t_kernel<<<dim3(24, 24), blk, 0, stream>>>(wo, wqkvoT + 3 * W, TDIM, TDIM);
    ln_kernel<true><<<dim3(NROWS, 3), blk, 0, stream>>>(
        q, k, v, ln1_g, ln1_b, qn, kn, vn);
    // merged QKV projection: z slices A (qn/kn/vn), BT (wq/wk/wv ^T), C (qh/kh/vh)
    gemm_kernel<false, false, false, false><<<dim3(6, 128, 3), blk, 0, stream>>>(
        qn, wqkvoT, nullptr, nullptr, qh, NROWS, TDIM, TDIM, S, W, S);
    attn_fused_kernel<<<dim3(1024), blk, 0, stream>>>(qh, qh + S, qh + 2 * S, att, attout);
    gemm_kernel<true, true, false, false><<<dim3(6, 128), blk, 0, stream>>>(
        attout, wqkvoT + 3 * W, wo_b, qn, y, NROWS, TDIM, TDIM, 0, 0, 0);
    cvt_t_kernel<<<dim3(96, 24), blk, 0, stream>>>(w1, w1T, TDIM, THID);
    cvt_t_kernel<<<dim3(24, 96), blk, 0, stream>>>(w2, w2T, THID, TDIM);
    ln_kernel<false><<<dim3(NROWS, 1), blk, 0, stream>>>(
        y, y, y, ln2_g, ln2_b, ln2y, ln2y, ln2y);
    gemm_kernel<true, false, true, false><<<dim3(24, 128), blk, 0, stream>>>(
        ln2y, w1T, b1, nullptr, hbuf, NROWS, THID, TDIM, 0, 0, 0);
    gemm_kernel<true, true, false, true><<<dim3(6, 128), blk, 0, stream>>>(
        hbuf, w2T, b2, y, out0, NROWS, TDIM, THID, 0, 0, 0);
}

// Round 2
// 702.210 us; speedup vs baseline: 1.0930x; 1.0930x over previous
//
#include <hip/hip_runtime.h>

// Transformer block. fp32 in/out, bf16 MFMA internal, fp32 accumulation.
// DIM=768 HID=3072 HEADS=8 DEPTH=96 SEQ=128 GROUPS(B*F)=128 ROWS=16384
// R4: fused MFMA attention (QK^T -> softmax -> PV in one kernel per head).
// R5: + XCD-aware bijective block swizzle in gemm_kernel (T1/m204);
//     + QKV projections merged into one grid.z=3 launch (A/B/C strided).
// R6: epilogue de-VALU: sigmoid-form GELU (exact identity, no tanhf),
//     per-row (not per-element) 64-bit index math, bias cached in regs,
//     staging source pointers hoisted out of the K-loop.
//     Evidence: FFN1 at VALUBusy=64% / MfmaUtil=20% -> epilogue VALU-bound.

#define NROWS 16384
#define TDIM 768
#define THID 3072
#define EPS 1e-5f

typedef short bf16x8 __attribute__((ext_vector_type(8)));
typedef float f32x4 __attribute__((ext_vector_type(4)));

__device__ __forceinline__ float b2f(unsigned short u) {
    union { unsigned int i; float f; } v; v.i = ((unsigned int)u) << 16; return v.f;
}
__device__ __forceinline__ unsigned short f2b(float f) {
    union { float f; unsigned int i; } v; v.f = f;
    unsigned int r = v.i + 0x7fffu + ((v.i >> 16) & 1u);
    return (unsigned short)(r >> 16);
}

// async 16B global -> LDS (lds dest is wave-uniform base; HW adds lane*16)
__device__ __forceinline__ void async_copy16(const unsigned short* g, unsigned short* l) {
    __builtin_amdgcn_global_load_lds(
        (const __attribute__((address_space(1))) unsigned int*)g,
        (__attribute__((address_space(3))) unsigned int*)l,
        16, 0, 0);
}

// ---------------- fp32 [K][N] -> bf16 transposed [N][K]
__global__ __launch_bounds__(256) void cvt_t_kernel(
    const float* __restrict__ src, unsigned short* __restrict__ dst, int K, int N)
{
    __shared__ unsigned short tile[32][33];
    int n0 = blockIdx.x * 32, k0 = blockIdx.y * 32;
    int tx = threadIdx.x & 31, ty = threadIdx.x >> 5;
#pragma unroll
    for (int r = ty; r < 32; r += 8)
        tile[r][tx] = f2b(src[(size_t)(k0 + r) * N + n0 + tx]);
    __syncthreads();
#pragma unroll
    for (int r = ty; r < 32; r += 8)
        dst[(size_t)(n0 + r) * K + k0 + tx] = tile[tx][r];
}

// ---------------- LayerNorm: one block per row, up to 3 tensors via blockIdx.y
template<bool IN_F32>
__global__ __launch_bounds__(256) void ln_kernel(
    const void* __restrict__ x0, const void* __restrict__ x1,
    const void* __restrict__ x2,
    const float* __restrict__ g, const float* __restrict__ bb,
    unsigned short* __restrict__ o0, unsigned short* __restrict__ o1,
    unsigned short* __restrict__ o2)
{
    int t = blockIdx.y;
    const void* x = (t == 0) ? x0 : (t == 1) ? x1 : x2;
    unsigned short* o = (t == 0) ? o0 : (t == 1) ? o1 : o2;
    size_t base = (size_t)blockIdx.x * TDIM;
    int tid = threadIdx.x;
    float v[3]; float sum = 0.f, sq = 0.f;
#pragma unroll
    for (int i = 0; i < 3; i++) {
        if constexpr (IN_F32) v[i] = ((const float*)x)[base + tid + i * 256];
        else v[i] = b2f(((const unsigned short*)x)[base + tid + i * 256]);
        sum += v[i]; sq += v[i] * v[i];
    }
#pragma unroll
    for (int o_ = 32; o_ > 0; o_ >>= 1) {
        sum += __shfl_down(sum, o_); sq += __shfl_down(sq, o_);
    }
    __shared__ float s1[4], s2[4];
    __shared__ float smu, srs;
    int wave = tid >> 6, lane = tid & 63;
    if (lane == 0) { s1[wave] = sum; s2[wave] = sq; }
    __syncthreads();
    if (tid == 0) {
        float S = s1[0] + s1[1] + s1[2] + s1[3];
        float Q = s2[0] + s2[1] + s2[2] + s2[3];
        float mu = S / (float)TDIM;
        float var = Q / (float)TDIM - mu * mu;
        smu = mu; srs = rsqrtf(var + EPS);
    }
    __syncthreads();
    float mu = smu, rs = srs;
#pragma unroll
    for (int i = 0; i < 3; i++) {
        int c = tid + i * 256;
        o[base + c] = f2b((v[i] - mu) * rs * g[c] + bb[c]);
    }
}

// ---------------- MFMA GEMM: C[M,N] = op(A[M,K] @ BT[N,K]^T (+bias)(+gelu)(+res))
// grid.z slices A/BT/C by aStride/bStride/cStride (elements) for batched QKV.
// Block mapping: XCD-aware bijective swizzle (T1, m204 formula).
template<bool BIAS, bool RES, bool GELU, bool OUTF32>
__global__ __launch_bounds__(256) void gemm_kernel(
    const unsigned short* __restrict__ A, const unsigned short* __restrict__ BT,
    const float* __restrict__ bias, const unsigned short* __restrict__ resid,
    void* __restrict__ Cv, int M, int N, int K,
    size_t aStride, size_t bStride, size_t cStride)
{
    __shared__ unsigned short sA[128][32];
    __shared__ unsigned short sB[128][32];
    int tid = threadIdx.x;

    // bijective XCD swizzle over the 2D grid
    int nbx = gridDim.x;
    int nwg = nbx * gridDim.y;
    int bid = blockIdx.y * nbx + blockIdx.x;
    int xcd = bid & 7, loc = bid >> 3;
    int qc = nwg >> 3, rc = nwg & 7;
    int swz = (xcd < rc ? xcd * (qc + 1) : rc * (qc + 1) + (xcd - rc) * qc) + loc;
    int row0 = (swz / nbx) * 128;
    int col0 = (swz % nbx) * 128;

    int z = blockIdx.z;
    A  += (size_t)z * aStride;
    BT += (size_t)z * bStride;
    size_t zoff = (size_t)z * cStride;

    int wave = tid >> 6, lane = tid & 63;
    int wm = (wave >> 1) * 64, wn = (wave & 1) * 64;
    int cl = lane & 15, quad = lane >> 4;

    f32x4 acc[4][4];
#pragma unroll
    for (int i = 0; i < 4; i++)
#pragma unroll
        for (int j = 0; j < 4; j++) acc[i][j] = (f32x4){0.f, 0.f, 0.f, 0.f};

    const unsigned short* Arow = A + (size_t)row0 * K;
    const unsigned short* Brow = BT + (size_t)col0 * K;

    // hoisted staging pointers (lane-fixed; only k0 varies in-loop)
    int c0 = wave * 128 + lane, c1 = c0 + 64;
    const unsigned short* aS0 = Arow + (size_t)(c0 >> 2) * K + ((c0 & 3) << 3);
    const unsigned short* aS1 = Arow + (size_t)(c1 >> 2) * K + ((c1 & 3) << 3);
    const unsigned short* bS0 = Brow + (size_t)(c0 >> 2) * K + ((c0 & 3) << 3);
    const unsigned short* bS1 = Brow + (size_t)(c1 >> 2) * K + ((c1 & 3) << 3);
    unsigned short* aD0 = &sA[0][0] + (size_t)(wave * 128) * 8;
    unsigned short* aD1 = aD0 + 64 * 8;
    unsigned short* bD0 = &sB[0][0] + (size_t)(wave * 128) * 8;
    unsigned short* bD1 = bD0 + 64 * 8;

    for (int k0 = 0; k0 < K; k0 += 32) {
        async_copy16(aS0 + k0, aD0);
        async_copy16(aS1 + k0, aD1);
        async_copy16(bS0 + k0, bD0);
        async_copy16(bS1 + k0, bD1);
        __syncthreads();
        bf16x8 af[4], bfr[4];
#pragma unroll
        for (int mi = 0; mi < 4; mi++)
            af[mi] = *(const bf16x8*)(&sA[wm + mi * 16 + cl][quad * 8]);
#pragma unroll
        for (int ni = 0; ni < 4; ni++)
            bfr[ni] = *(const bf16x8*)(&sB[wn + ni * 16 + cl][quad * 8]);
#pragma unroll
        for (int mi = 0; mi < 4; mi++)
#pragma unroll
            for (int ni = 0; ni < 4; ni++)
                acc[mi][ni] = __builtin_amdgcn_mfma_f32_16x16x32_bf16(
                    af[mi], bfr[ni], acc[mi][ni], 0, 0, 0);
        __syncthreads();
    }

    // ---- epilogue: bias cached, one 64-bit row computation per output row
    float bvv[4];
#pragma unroll
    for (int ni = 0; ni < 4; ni++) {
        if constexpr (BIAS) bvv[ni] = bias[col0 + wn + ni * 16 + cl];
        else bvv[ni] = 0.f;
    }
#pragma unroll
    for (int mi = 0; mi < 4; mi++) {
#pragma unroll
        for (int r = 0; r < 4; r++) {
            int gr = row0 + wm + mi * 16 + quad * 4 + r;
            size_t rb = (size_t)gr * N + col0 + wn + cl;
#pragma unroll
            for (int ni = 0; ni < 4; ni++) {
                float v = acc[mi][ni][r];
                if constexpr (BIAS) v += bvv[ni];
                if constexpr (GELU) {
                    // 0.5x(1+tanh(u)) == x * sigmoid(2u)  (exact identity)
                    float x = v;
                    float t = x + 0.044715f * x * x * x;
                    float e = __expf(-1.5957691216057308f * t);  // 2*sqrt(2/pi)
                    v = x * __builtin_amdgcn_rcpf(1.0f + e);
                }
                if constexpr (RES) v += b2f(resid[rb + ni * 16]);
                size_t idx = rb + ni * 16 + zoff;
                if constexpr (OUTF32) ((float*)Cv)[idx] = v;
                else ((unsigned short*)Cv)[idx] = f2b(v);
            }
        }
    }
}

// ---------------- Fused attention: per-head QK^T -> softmax -> att + PV
// Block = 256 threads (4 waves), grid = 1024 heads.
// Phase1: S(128x128) via MFMA, wave quadrants 64x64.
// Softmax: register rows + 16-lane shfl + LDS exchange across wave pair.
// Phase2: O = P(128x128) @ V(128x96) via MFMA, wave = 32 rows x 96 cols.
__global__ __launch_bounds__(256) void attn_fused_kernel(
    const unsigned short* __restrict__ qh, const unsigned short* __restrict__ kh,
    const unsigned short* __restrict__ vh, float* __restrict__ att,
    unsigned short* __restrict__ attout)
{
    __shared__ __align__(16) unsigned short smem[30464];
    __shared__ float wmax[2][128];
    __shared__ float wsum[2][128];
    __shared__ float sInv[128];
    // phase1 aliases: sQ = smem[0..12287] [128][96], sK = smem[12288..] [128][96]
    // phase2 aliases: sP = smem[0..17407] [128][136], sVt = smem[17408..] [96][136]
    unsigned short* sQ = smem;
    unsigned short* sK = smem + 12288;
    unsigned short* sP = smem;
    unsigned short* sVt = smem + 17408;

    int hb = blockIdx.x, g = hb >> 3, h = hb & 7;
    int tid = threadIdx.x;
    int wave = tid >> 6, lane = tid & 63;
    int cl = lane & 15, quad = lane >> 4;
    int wm = (wave >> 1) * 64, wn = (wave & 1) * 64;

    size_t rbase = (size_t)g * 128 * TDIM + (size_t)h * 96;

    // ---- stage Q,K: 1536 16B-chunks each; chunk c -> LDS offset c*16B (linear)
#pragma unroll
    for (int it = 0; it < 6; it++) {
        int cb = wave * 384 + it * 64;
        int c = cb + lane;
        int r = c / 12, dc = (c % 12) * 8;
        async_copy16(qh + rbase + (size_t)r * TDIM + dc, sQ + (size_t)cb * 8);
        async_copy16(kh + rbase + (size_t)r * TDIM + dc, sK + (size_t)cb * 8);
    }
    __syncthreads();

    // ---- Phase 1: S = Q @ K^T (wave quadrant 64x64), K-dim 96 = 3 steps
    f32x4 acc[4][4];
#pragma unroll
    for (int i = 0; i < 4; i++)
#pragma unroll
        for (int j = 0; j < 4; j++) acc[i][j] = (f32x4){0.f, 0.f, 0.f, 0.f};
#pragma unroll
    for (int kk = 0; kk < 3; kk++) {
        bf16x8 af[4], bfr[4];
#pragma unroll
        for (int mi = 0; mi < 4; mi++)
            af[mi] = *(const bf16x8*)(sQ + (size_t)(wm + mi * 16 + cl) * 96 + kk * 32 + quad * 8);
#pragma unroll
        for (int ni = 0; ni < 4; ni++)
            bfr[ni] = *(const bf16x8*)(sK + (size_t)(wn + ni * 16 + cl) * 96 + kk * 32 + quad * 8);
#pragma unroll
        for (int mi = 0; mi < 4; mi++)
#pragma unroll
            for (int ni = 0; ni < 4; ni++)
                acc[mi][ni] = __builtin_amdgcn_mfma_f32_16x16x32_bf16(
                    af[mi], bfr[ni], acc[mi][ni], 0, 0, 0);
    }

    // ---- scale + row max (C layout: col=cl, row=quad*4+r within frag)
    const float scale = 0.10206207261596575f;  // 96^-0.5
#pragma unroll
    for (int mi = 0; mi < 4; mi++)
#pragma unroll
        for (int ni = 0; ni < 4; ni++)
#pragma unroll
            for (int r = 0; r < 4; r++) acc[mi][ni][r] *= scale;
#pragma unroll
    for (int mi = 0; mi < 4; mi++) {
#pragma unroll
        for (int r = 0; r < 4; r++) {
            float m = fmaxf(fmaxf(acc[mi][0][r], acc[mi][1][r]),
                            fmaxf(acc[mi][2][r], acc[mi][3][r]));
            m = fmaxf(m, __shfl_xor(m, 1));
            m = fmaxf(m, __shfl_xor(m, 2));
            m = fmaxf(m, __shfl_xor(m, 4));
            m = fmaxf(m, __shfl_xor(m, 8));
            if (cl == 0) wmax[wn >> 6][wm + mi * 16 + quad * 4 + r] = m;
        }
    }
    __syncthreads();  // b1: wmax ready; sQ/sK dead from here

    // ---- stage V^T into sVt[96][136] (staggered j to spread banks)
    for (int c = tid; c < 1536; c += 256) {
        int kk2 = c / 12, dc2 = (c % 12) * 8;
        uint4 t_ = *(const uint4*)(vh + rbase + (size_t)kk2 * TDIM + dc2);
        unsigned short* tp = (unsigned short*)&t_;
#pragma unroll
        for (int j = 0; j < 8; j++) {
            int jj = (j + tid) & 7;
            sVt[(size_t)(dc2 + jj) * 136 + kk2] = tp[jj];
        }
    }

    // ---- exp (unnormalized), row sum, write P(bf16) to sP
#pragma unroll
    for (int mi = 0; mi < 4; mi++) {
#pragma unroll
        for (int r = 0; r < 4; r++) {
            int row = wm + mi * 16 + quad * 4 + r;
            float rm = fmaxf(wmax[0][row], wmax[1][row]);
            float s = 0.f;
#pragma unroll
            for (int ni = 0; ni < 4; ni++) {
                float e = __expf(acc[mi][ni][r] - rm);
                acc[mi][ni][r] = e;
                s += e;
            }
            s += __shfl_xor(s, 1);
            s += __shfl_xor(s, 2);
            s += __shfl_xor(s, 4);
            s += __shfl_xor(s, 8);
            if (cl == 0) wsum[wn >> 6][row] = s;
#pragma unroll
            for (int ni = 0; ni < 4; ni++)
                sP[(size_t)row * 136 + wn + ni * 16 + cl] = f2b(acc[mi][ni][r]);
        }
    }
    __syncthreads();  // b2: wsum, sP, sVt ready

    if (tid < 128) sInv[tid] = 1.0f / (wsum[0][tid] + wsum[1][tid]);
    __syncthreads();  // b3: sInv ready

    // ---- write normalized att (fp32 output 1)
    size_t pbase = (size_t)hb * 128 * 128;
#pragma unroll
    for (int mi = 0; mi < 4; mi++) {
#pragma unroll
        for (int r = 0; r < 4; r++) {
            int row = wm + mi * 16 + quad * 4 + r;
            float iv = sInv[row];
#pragma unroll
            for (int ni = 0; ni < 4; ni++)
                att[pbase + (size_t)row * 128 + wn + ni * 16 + cl] =
                    acc[mi][ni][r] * iv;
        }
    }

    // ---- Phase 2: O = P @ V  (wave = rows [wave*32, wave*32+32), cols 0..95)
    int wm2 = wave * 32;
    f32x4 acc2[2][6];
#pragma unroll
    for (int i = 0; i < 2; i++)
#pragma unroll
        for (int j = 0; j < 6; j++) acc2[i][j] = (f32x4){0.f, 0.f, 0.f, 0.f};
#pragma unroll
    for (int ks = 0; ks < 4; ks++) {
        bf16x8 pa[2], vb[6];
#pragma unroll
        for (int mi2 = 0; mi2 < 2; mi2++)
            pa[mi2] = *(const bf16x8*)(sP + (size_t)(wm2 + mi2 * 16 + cl) * 136 + ks * 32 + quad * 8);
#pragma unroll
        for (int ni2 = 0; ni2 < 6; ni2++)
            vb[ni2] = *(const bf16x8*)(sVt + (size_t)(ni2 * 16 + cl) * 136 + ks * 32 + quad * 8);
#pragma unroll
        for (int mi2 = 0; mi2 < 2; mi2++)
#pragma unroll
            for (int ni2 = 0; ni2 < 6; ni2++)
                acc2[mi2][ni2] = __builtin_amdgcn_mfma_f32_16x16x32_bf16(
                    pa[mi2], vb[ni2], acc2[mi2][ni2], 0, 0, 0);
    }
    // epilogue: attout[row][h*96 + d] = O * inv[row]
#pragma unroll
    for (int mi2 = 0; mi2 < 2; mi2++) {
#pragma unroll
        for (int r = 0; r < 4; r++) {
            int row = wm2 + mi2 * 16 + quad * 4 + r;
            float iv = sInv[row];
#pragma unroll
            for (int ni2 = 0; ni2 < 6; ni2++) {
                int d = ni2 * 16 + cl;
                attout[rbase + (size_t)row * TDIM + d] =
                    f2b(acc2[mi2][ni2][r] * iv);
            }
        }
    }
}

extern "C" void kernel_launch(void* const* d_in, const int* in_sizes, int n_in,
                              void* d_out, int out_size, void* d_ws, size_t ws_size,
                              hipStream_t stream)
{
    const float* q     = (const float*)d_in[0];
    const float* k     = (const float*)d_in[1];
    const float* v     = (const float*)d_in[2];
    const float* ln1_g = (const float*)d_in[3];
    const float* ln1_b = (const float*)d_in[4];
    const float* wq    = (const float*)d_in[5];
    const float* wk    = (const float*)d_in[6];
    const float* wv    = (const float*)d_in[7];
    const float* wo    = (const float*)d_in[8];
    const float* wo_b  = (const float*)d_in[9];
    const float* ln2_g = (const float*)d_in[10];
    const float* ln2_b = (const float*)d_in[11];
    const float* w1    = (const float*)d_in[12];
    const float* b1    = (const float*)d_in[13];
    const float* w2    = (const float*)d_in[14];
    const float* b2    = (const float*)d_in[15];

    float* out0 = (float*)d_out;
    const size_t S = (size_t)NROWS * TDIM;  // 12,582,912
    float* att = out0 + S;                  // output 1: (2,64,8,128,128) fp32
    unsigned short* ws = (unsigned short*)d_ws;
    if (ws_size < 7 * S * sizeof(unsigned short)) return;  // need ~168 MB

    const size_t W = (size_t)TDIM * TDIM;   // 589,824
    const size_t W2 = (size_t)TDIM * THID;  // 2,359,296

    unsigned short* qn     = ws;          // slot0; later ln2y
    unsigned short* kn     = ws + S;      // slot1; later attout, then w1T/w2T
    unsigned short* vn     = ws + 2 * S;  // slot2; later y
    unsigned short* qh     = ws + 3 * S;  // slot3..5: qh/kh/vh; later hbuf (3..6)
    unsigned short* wqkvoT = ws + 6 * S;  // slot6: wq/wk/wv/wo ^T bf16 (dead at ffn1)
    unsigned short* attout = ws + S;
    unsigned short* y      = ws + 2 * S;
    unsigned short* ln2y   = ws;
    unsigned short* w1T    = ws + S;      // [3072][768], after attout dead
    unsigned short* w2T    = ws + S + W2; // [768][3072]
    unsigned short* hbuf   = ws + 3 * S;  // 16384 x 3072 (4S)

    dim3 blk(256);
    cvt_t_kernel<<<dim3(24, 24), blk, 0, stream>>>(wq, wqkvoT + 0 * W, TDIM, TDIM);
    cvt_t_kernel<<<dim3(24, 24), blk, 0, stream>>>(wk, wqkvoT + 1 * W, TDIM, TDIM);
    cvt_t_kernel<<<dim3(24, 24), blk, 0, stream>>>(wv, wqkvoT + 2 * W, TDIM, TDIM);
    cvt_t_kernel<<<dim3(24, 24), blk, 0, stream>>>(wo, wqkvoT + 3 * W, TDIM, TDIM);
    ln_kernel<true><<<dim3(NROWS, 3), blk, 0, stream>>>(
        q, k, v, ln1_g, ln1_b, qn, kn, vn);
    // merged QKV projection: z slices A (qn/kn/vn), BT (wq/wk/wv ^T), C (qh/kh/vh)
    gemm_kernel<false, false, false, false><<<dim3(6, 128, 3), blk, 0, stream>>>(
        qn, wqkvoT, nullptr, nullptr, qh, NROWS, TDIM, TDIM, S, W, S);
    attn_fused_kernel<<<dim3(1024), blk, 0, stream>>>(qh, qh + S, qh + 2 * S, att, attout);
    gemm_kernel<true, true, false, false><<<dim3(6, 128), blk, 0, stream>>>(
        attout, wqkvoT + 3 * W, wo_b, qn, y, NROWS, TDIM, TDIM, 0, 0, 0);
    cvt_t_kernel<<<dim3(96, 24), blk, 0, stream>>>(w1, w1T, TDIM, THID);
    cvt_t_kernel<<<dim3(24, 96), blk, 0, stream>>>(w2, w2T, THID, TDIM);
    ln_kernel<false><<<dim3(NROWS, 1), blk, 0, stream>>>(
        y, y, y, ln2_g, ln2_b, ln2y, ln2y, ln2y);
    gemm_kernel<true, false, true, false><<<dim3(24, 128), blk, 0, stream>>>(
        ln2y, w1T, b1, nullptr, hbuf, NROWS, THID, TDIM, 0, 0, 0);
    gemm_kernel<true, true, false, true><<<dim3(6, 128), blk, 0, stream>>>(
        hbuf, w2T, b2, y, out0, NROWS, TDIM, THID, 0, 0, 0);
}

// Round 4
// 691.406 us; speedup vs baseline: 1.1101x; 1.0156x over previous
//
#include <hip/hip_runtime.h>

// Transformer block. fp32 in/out, bf16 MFMA internal, fp32 accumulation.
// DIM=768 HID=3072 HEADS=8 DEPTH=96 SEQ=128 GROUPS(B*F)=128 ROWS=16384
// R4: fused MFMA attention (QK^T -> softmax -> PV in one kernel per head).
// R5: + XCD swizzle (T1/m204); QKV merged grid.z=3.
// R6: epilogue de-VALU (sigmoid-GELU, per-row index math, cached bias).
// R7: FFN1 -> new gemm256_kernel: 256x256 tile, 8 waves, BK=32, double-buffered
//     LDS with counted s_waitcnt vmcnt(4) across raw s_barriers (T4: loads stay
//     in flight through compute), T2 lane-constant XOR swizzle (conflict-free
//     ds_read_b128), pre-swizzled global source + linear LDS dest (rule #21).
// R8: identical resubmission of R7 (round-3 broker failure matched round-0's
//     known infra flake; hang/race audit of gemm256 found no kernel-side cause).

#define NROWS 16384
#define TDIM 768
#define THID 3072
#define EPS 1e-5f

typedef short bf16x8 __attribute__((ext_vector_type(8)));
typedef float f32x4 __attribute__((ext_vector_type(4)));

__device__ __forceinline__ float b2f(unsigned short u) {
    union { unsigned int i; float f; } v; v.i = ((unsigned int)u) << 16; return v.f;
}
__device__ __forceinline__ unsigned short f2b(float f) {
    union { float f; unsigned int i; } v; v.f = f;
    unsigned int r = v.i + 0x7fffu + ((v.i >> 16) & 1u);
    return (unsigned short)(r >> 16);
}

// async 16B global -> LDS (lds dest is wave-uniform base; HW adds lane*16)
__device__ __forceinline__ void async_copy16(const unsigned short* g, unsigned short* l) {
    __builtin_amdgcn_global_load_lds(
        (const __attribute__((address_space(1))) unsigned int*)g,
        (__attribute__((address_space(3))) unsigned int*)l,
        16, 0, 0);
}

// ---------------- fp32 [K][N] -> bf16 transposed [N][K]
__global__ __launch_bounds__(256) void cvt_t_kernel(
    const float* __restrict__ src, unsigned short* __restrict__ dst, int K, int N)
{
    __shared__ unsigned short tile[32][33];
    int n0 = blockIdx.x * 32, k0 = blockIdx.y * 32;
    int tx = threadIdx.x & 31, ty = threadIdx.x >> 5;
#pragma unroll
    for (int r = ty; r < 32; r += 8)
        tile[r][tx] = f2b(src[(size_t)(k0 + r) * N + n0 + tx]);
    __syncthreads();
#pragma unroll
    for (int r = ty; r < 32; r += 8)
        dst[(size_t)(n0 + r) * K + k0 + tx] = tile[tx][r];
}

// ---------------- LayerNorm: one block per row, up to 3 tensors via blockIdx.y
template<bool IN_F32>
__global__ __launch_bounds__(256) void ln_kernel(
    const void* __restrict__ x0, const void* __restrict__ x1,
    const void* __restrict__ x2,
    const float* __restrict__ g, const float* __restrict__ bb,
    unsigned short* __restrict__ o0, unsigned short* __restrict__ o1,
    unsigned short* __restrict__ o2)
{
    int t = blockIdx.y;
    const void* x = (t == 0) ? x0 : (t == 1) ? x1 : x2;
    unsigned short* o = (t == 0) ? o0 : (t == 1) ? o1 : o2;
    size_t base = (size_t)blockIdx.x * TDIM;
    int tid = threadIdx.x;
    float v[3]; float sum = 0.f, sq = 0.f;
#pragma unroll
    for (int i = 0; i < 3; i++) {
        if constexpr (IN_F32) v[i] = ((const float*)x)[base + tid + i * 256];
        else v[i] = b2f(((const unsigned short*)x)[base + tid + i * 256]);
        sum += v[i]; sq += v[i] * v[i];
    }
#pragma unroll
    for (int o_ = 32; o_ > 0; o_ >>= 1) {
        sum += __shfl_down(sum, o_); sq += __shfl_down(sq, o_);
    }
    __shared__ float s1[4], s2[4];
    __shared__ float smu, srs;
    int wave = tid >> 6, lane = tid & 63;
    if (lane == 0) { s1[wave] = sum; s2[wave] = sq; }
    __syncthreads();
    if (tid == 0) {
        float S = s1[0] + s1[1] + s1[2] + s1[3];
        float Q = s2[0] + s2[1] + s2[2] + s2[3];
        float mu = S / (float)TDIM;
        float var = Q / (float)TDIM - mu * mu;
        smu = mu; srs = rsqrtf(var + EPS);
    }
    __syncthreads();
    float mu = smu, rs = srs;
#pragma unroll
    for (int i = 0; i < 3; i++) {
        int c = tid + i * 256;
        o[base + c] = f2b((v[i] - mu) * rs * g[c] + bb[c]);
    }
}

// ---------------- MFMA GEMM (128x128 tile): C = op(A @ BT^T (+bias)(+gelu)(+res))
template<bool BIAS, bool RES, bool GELU, bool OUTF32>
__global__ __launch_bounds__(256) void gemm_kernel(
    const unsigned short* __restrict__ A, const unsigned short* __restrict__ BT,
    const float* __restrict__ bias, const unsigned short* __restrict__ resid,
    void* __restrict__ Cv, int M, int N, int K,
    size_t aStride, size_t bStride, size_t cStride)
{
    __shared__ unsigned short sA[128][32];
    __shared__ unsigned short sB[128][32];
    int tid = threadIdx.x;

    int nbx = gridDim.x;
    int nwg = nbx * gridDim.y;
    int bid = blockIdx.y * nbx + blockIdx.x;
    int xcd = bid & 7, loc = bid >> 3;
    int qc = nwg >> 3, rc = nwg & 7;
    int swz = (xcd < rc ? xcd * (qc + 1) : rc * (qc + 1) + (xcd - rc) * qc) + loc;
    int row0 = (swz / nbx) * 128;
    int col0 = (swz % nbx) * 128;

    int z = blockIdx.z;
    A  += (size_t)z * aStride;
    BT += (size_t)z * bStride;
    size_t zoff = (size_t)z * cStride;

    int wave = tid >> 6, lane = tid & 63;
    int wm = (wave >> 1) * 64, wn = (wave & 1) * 64;
    int cl = lane & 15, quad = lane >> 4;

    f32x4 acc[4][4];
#pragma unroll
    for (int i = 0; i < 4; i++)
#pragma unroll
        for (int j = 0; j < 4; j++) acc[i][j] = (f32x4){0.f, 0.f, 0.f, 0.f};

    const unsigned short* Arow = A + (size_t)row0 * K;
    const unsigned short* Brow = BT + (size_t)col0 * K;

    int c0 = wave * 128 + lane, c1 = c0 + 64;
    const unsigned short* aS0 = Arow + (size_t)(c0 >> 2) * K + ((c0 & 3) << 3);
    const unsigned short* aS1 = Arow + (size_t)(c1 >> 2) * K + ((c1 & 3) << 3);
    const unsigned short* bS0 = Brow + (size_t)(c0 >> 2) * K + ((c0 & 3) << 3);
    const unsigned short* bS1 = Brow + (size_t)(c1 >> 2) * K + ((c1 & 3) << 3);
    unsigned short* aD0 = &sA[0][0] + (size_t)(wave * 128) * 8;
    unsigned short* aD1 = aD0 + 64 * 8;
    unsigned short* bD0 = &sB[0][0] + (size_t)(wave * 128) * 8;
    unsigned short* bD1 = bD0 + 64 * 8;

    for (int k0 = 0; k0 < K; k0 += 32) {
        async_copy16(aS0 + k0, aD0);
        async_copy16(aS1 + k0, aD1);
        async_copy16(bS0 + k0, bD0);
        async_copy16(bS1 + k0, bD1);
        __syncthreads();
        bf16x8 af[4], bfr[4];
#pragma unroll
        for (int mi = 0; mi < 4; mi++)
            af[mi] = *(const bf16x8*)(&sA[wm + mi * 16 + cl][quad * 8]);
#pragma unroll
        for (int ni = 0; ni < 4; ni++)
            bfr[ni] = *(const bf16x8*)(&sB[wn + ni * 16 + cl][quad * 8]);
#pragma unroll
        for (int mi = 0; mi < 4; mi++)
#pragma unroll
            for (int ni = 0; ni < 4; ni++)
                acc[mi][ni] = __builtin_amdgcn_mfma_f32_16x16x32_bf16(
                    af[mi], bfr[ni], acc[mi][ni], 0, 0, 0);
        __syncthreads();
    }

    float bvv[4];
#pragma unroll
    for (int ni = 0; ni < 4; ni++) {
        if constexpr (BIAS) bvv[ni] = bias[col0 + wn + ni * 16 + cl];
        else bvv[ni] = 0.f;
    }
#pragma unroll
    for (int mi = 0; mi < 4; mi++) {
#pragma unroll
        for (int r = 0; r < 4; r++) {
            int gr = row0 + wm + mi * 16 + quad * 4 + r;
            size_t rb = (size_t)gr * N + col0 + wn + cl;
#pragma unroll
            for (int ni = 0; ni < 4; ni++) {
                float v = acc[mi][ni][r];
                if constexpr (BIAS) v += bvv[ni];
                if constexpr (GELU) {
                    float x = v;
                    float t = x + 0.044715f * x * x * x;
                    float e = __expf(-1.5957691216057308f * t);
                    v = x * __builtin_amdgcn_rcpf(1.0f + e);
                }
                if constexpr (RES) v += b2f(resid[rb + ni * 16]);
                size_t idx = rb + ni * 16 + zoff;
                if constexpr (OUTF32) ((float*)Cv)[idx] = v;
                else ((unsigned short*)Cv)[idx] = f2b(v);
            }
        }
    }
}

// ---------------- MFMA GEMM (256x256 tile, 8 waves, BK=32, double-buffered):
// counted s_waitcnt vmcnt(4) across raw barriers (T4) + lane-constant XOR
// swizzle (T2). LDS[r][slot] = global[r][slot ^ ((r>>1)&3)]; read slot =
// quad ^ ((cl>>1)&3) retrieves global[r][quad]. Same involution both sides.
template<bool BIAS, bool GELU>
__global__ __launch_bounds__(512) void gemm256_kernel(
    const unsigned short* __restrict__ A, const unsigned short* __restrict__ BT,
    const float* __restrict__ bias, unsigned short* __restrict__ C,
    int N, int K)
{
    __shared__ unsigned short sA[2][256][32];   // 32 KiB
    __shared__ unsigned short sB[2][256][32];   // 32 KiB  (64 KiB total)
    int tid = threadIdx.x;

    int nbx = gridDim.x;
    int nwg = nbx * gridDim.y;
    int bid = blockIdx.y * nbx + blockIdx.x;
    int xcd = bid & 7, loc = bid >> 3;
    int qc = nwg >> 3, rc = nwg & 7;
    int swz = (xcd < rc ? xcd * (qc + 1) : rc * (qc + 1) + (xcd - rc) * qc) + loc;
    int row0 = (swz / nbx) * 256;
    int col0 = (swz % nbx) * 256;

    int wave = tid >> 6, lane = tid & 63;
    int wr = wave >> 2, wc = wave & 3;           // 2M x 4N waves
    int cl = lane & 15, quad = lane >> 4;
    int sl8 = (quad ^ ((cl >> 1) & 3)) << 3;     // swizzled 16B slot (elements)

    // staging source (chunk c = tid (+512); row=c>>2, slot=c&3, pre-swizzled)
    size_t rowoff = (size_t)(tid >> 2) * K + (size_t)(((tid & 3) ^ ((tid >> 3) & 3)) << 3);
    const unsigned short* aS0 = A + (size_t)row0 * K + rowoff;
    const unsigned short* aS1 = aS0 + (size_t)128 * K;
    const unsigned short* bS0 = BT + (size_t)col0 * K + rowoff;
    const unsigned short* bS1 = bS0 + (size_t)128 * K;
    unsigned short* aD = &sA[0][0][0] + (wave * 64) * 8;   // +buf*8192, +half*4096
    unsigned short* bD = &sB[0][0][0] + (wave * 64) * 8;

    f32x4 acc[8][4];
#pragma unroll
    for (int i = 0; i < 8; i++)
#pragma unroll
        for (int j = 0; j < 4; j++) acc[i][j] = (f32x4){0.f, 0.f, 0.f, 0.f};

    int NT = K >> 5;
    // prologue: stage tile 0 -> buf 0
    async_copy16(aS0, aD);
    async_copy16(aS1, aD + 4096);
    async_copy16(bS0, bD);
    async_copy16(bS1, bD + 4096);

    for (int t = 0; t < NT; ++t) {
        int cur = t & 1;
        if (t + 1 < NT) {
            int nb = (cur ^ 1) * 8192;
            int ko = (t + 1) << 5;
            async_copy16(aS0 + ko, aD + nb);
            async_copy16(aS1 + ko, aD + nb + 4096);
            async_copy16(bS0 + ko, bD + nb);
            async_copy16(bS1 + ko, bD + nb + 4096);
            asm volatile("s_waitcnt vmcnt(4)" ::: "memory");  // tile t landed; t+1 in flight
        } else {
            asm volatile("s_waitcnt vmcnt(0)" ::: "memory");  // final tile: drain
        }
        __builtin_amdgcn_s_barrier();                 // buf[cur] valid block-wide
        __builtin_amdgcn_sched_barrier(0);
        const unsigned short* pA = &sA[cur][0][0];
        const unsigned short* pB = &sB[cur][0][0];
        bf16x8 bfr[4], af[4];
#pragma unroll
        for (int ni = 0; ni < 4; ni++)
            bfr[ni] = *(const bf16x8*)(pB + (wc * 64 + ni * 16 + cl) * 32 + sl8);
#pragma unroll
        for (int mi = 0; mi < 4; mi++)
            af[mi] = *(const bf16x8*)(pA + (wr * 128 + mi * 16 + cl) * 32 + sl8);
#pragma unroll
        for (int mi = 0; mi < 4; mi++)
#pragma unroll
            for (int ni = 0; ni < 4; ni++)
                acc[mi][ni] = __builtin_amdgcn_mfma_f32_16x16x32_bf16(
                    af[mi], bfr[ni], acc[mi][ni], 0, 0, 0);
#pragma unroll
        for (int mi = 0; mi < 4; mi++)
            af[mi] = *(const bf16x8*)(pA + (wr * 128 + 64 + mi * 16 + cl) * 32 + sl8);
#pragma unroll
        for (int mi = 0; mi < 4; mi++)
#pragma unroll
            for (int ni = 0; ni < 4; ni++)
                acc[mi + 4][ni] = __builtin_amdgcn_mfma_f32_16x16x32_bf16(
                    af[mi], bfr[ni], acc[mi + 4][ni], 0, 0, 0);
        __builtin_amdgcn_sched_barrier(0);
        __builtin_amdgcn_s_barrier();                 // all reads of buf[cur] done
        __builtin_amdgcn_sched_barrier(0);
    }

    float bvv[4];
#pragma unroll
    for (int ni = 0; ni < 4; ni++) {
        if constexpr (BIAS) bvv[ni] = bias[col0 + wc * 64 + ni * 16 + cl];
        else bvv[ni] = 0.f;
    }
#pragma unroll
    for (int mi = 0; mi < 8; mi++) {
#pragma unroll
        for (int r = 0; r < 4; r++) {
            int gr = row0 + wr * 128 + mi * 16 + quad * 4 + r;
            size_t rb = (size_t)gr * N + col0 + wc * 64 + cl;
#pragma unroll
            for (int ni = 0; ni < 4; ni++) {
                float v = acc[mi][ni][r] + bvv[ni];
                if constexpr (GELU) {
                    float x = v;
                    float tt = x + 0.044715f * x * x * x;
                    float e = __expf(-1.5957691216057308f * tt);
                    v = x * __builtin_amdgcn_rcpf(1.0f + e);
                }
                C[rb + ni * 16] = f2b(v);
            }
        }
    }
}

// ---------------- Fused attention: per-head QK^T -> softmax -> att + PV
__global__ __launch_bounds__(256) void attn_fused_kernel(
    const unsigned short* __restrict__ qh, const unsigned short* __restrict__ kh,
    const unsigned short* __restrict__ vh, float* __restrict__ att,
    unsigned short* __restrict__ attout)
{
    __shared__ __align__(16) unsigned short smem[30464];
    __shared__ float wmax[2][128];
    __shared__ float wsum[2][128];
    __shared__ float sInv[128];
    unsigned short* sQ = smem;
    unsigned short* sK = smem + 12288;
    unsigned short* sP = smem;
    unsigned short* sVt = smem + 17408;

    int hb = blockIdx.x, g = hb >> 3, h = hb & 7;
    int tid = threadIdx.x;
    int wave = tid >> 6, lane = tid & 63;
    int cl = lane & 15, quad = lane >> 4;
    int wm = (wave >> 1) * 64, wn = (wave & 1) * 64;

    size_t rbase = (size_t)g * 128 * TDIM + (size_t)h * 96;

#pragma unroll
    for (int it = 0; it < 6; it++) {
        int cb = wave * 384 + it * 64;
        int c = cb + lane;
        int r = c / 12, dc = (c % 12) * 8;
        async_copy16(qh + rbase + (size_t)r * TDIM + dc, sQ + (size_t)cb * 8);
        async_copy16(kh + rbase + (size_t)r * TDIM + dc, sK + (size_t)cb * 8);
    }
    __syncthreads();

    f32x4 acc[4][4];
#pragma unroll
    for (int i = 0; i < 4; i++)
#pragma unroll
        for (int j = 0; j < 4; j++) acc[i][j] = (f32x4){0.f, 0.f, 0.f, 0.f};
#pragma unroll
    for (int kk = 0; kk < 3; kk++) {
        bf16x8 af[4], bfr[4];
#pragma unroll
        for (int mi = 0; mi < 4; mi++)
            af[mi] = *(const bf16x8*)(sQ + (size_t)(wm + mi * 16 + cl) * 96 + kk * 32 + quad * 8);
#pragma unroll
        for (int ni = 0; ni < 4; ni++)
            bfr[ni] = *(const bf16x8*)(sK + (size_t)(wn + ni * 16 + cl) * 96 + kk * 32 + quad * 8);
#pragma unroll
        for (int mi = 0; mi < 4; mi++)
#pragma unroll
            for (int ni = 0; ni < 4; ni++)
                acc[mi][ni] = __builtin_amdgcn_mfma_f32_16x16x32_bf16(
                    af[mi], bfr[ni], acc[mi][ni], 0, 0, 0);
    }

    const float scale = 0.10206207261596575f;  // 96^-0.5
#pragma unroll
    for (int mi = 0; mi < 4; mi++)
#pragma unroll
        for (int ni = 0; ni < 4; ni++)
#pragma unroll
            for (int r = 0; r < 4; r++) acc[mi][ni][r] *= scale;
#pragma unroll
    for (int mi = 0; mi < 4; mi++) {
#pragma unroll
        for (int r = 0; r < 4; r++) {
            float m = fmaxf(fmaxf(acc[mi][0][r], acc[mi][1][r]),
                            fmaxf(acc[mi][2][r], acc[mi][3][r]));
            m = fmaxf(m, __shfl_xor(m, 1));
            m = fmaxf(m, __shfl_xor(m, 2));
            m = fmaxf(m, __shfl_xor(m, 4));
            m = fmaxf(m, __shfl_xor(m, 8));
            if (cl == 0) wmax[wn >> 6][wm + mi * 16 + quad * 4 + r] = m;
        }
    }
    __syncthreads();

    for (int c = tid; c < 1536; c += 256) {
        int kk2 = c / 12, dc2 = (c % 12) * 8;
        uint4 t_ = *(const uint4*)(vh + rbase + (size_t)kk2 * TDIM + dc2);
        unsigned short* tp = (unsigned short*)&t_;
#pragma unroll
        for (int j = 0; j < 8; j++) {
            int jj = (j + tid) & 7;
            sVt[(size_t)(dc2 + jj) * 136 + kk2] = tp[jj];
        }
    }

#pragma unroll
    for (int mi = 0; mi < 4; mi++) {
#pragma unroll
        for (int r = 0; r < 4; r++) {
            int row = wm + mi * 16 + quad * 4 + r;
            float rm = fmaxf(wmax[0][row], wmax[1][row]);
            float s = 0.f;
#pragma unroll
            for (int ni = 0; ni < 4; ni++) {
                float e = __expf(acc[mi][ni][r] - rm);
                acc[mi][ni][r] = e;
                s += e;
            }
            s += __shfl_xor(s, 1);
            s += __shfl_xor(s, 2);
            s += __shfl_xor(s, 4);
            s += __shfl_xor(s, 8);
            if (cl == 0) wsum[wn >> 6][row] = s;
#pragma unroll
            for (int ni = 0; ni < 4; ni++)
                sP[(size_t)row * 136 + wn + ni * 16 + cl] = f2b(acc[mi][ni][r]);
        }
    }
    __syncthreads();

    if (tid < 128) sInv[tid] = 1.0f / (wsum[0][tid] + wsum[1][tid]);
    __syncthreads();

    size_t pbase = (size_t)hb * 128 * 128;
#pragma unroll
    for (int mi = 0; mi < 4; mi++) {
#pragma unroll
        for (int r = 0; r < 4; r++) {
            int row = wm + mi * 16 + quad * 4 + r;
            float iv = sInv[row];
#pragma unroll
            for (int ni = 0; ni < 4; ni++)
                att[pbase + (size_t)row * 128 + wn + ni * 16 + cl] =
                    acc[mi][ni][r] * iv;
        }
    }

    int wm2 = wave * 32;
    f32x4 acc2[2][6];
#pragma unroll
    for (int i = 0; i < 2; i++)
#pragma unroll
        for (int j = 0; j < 6; j++) acc2[i][j] = (f32x4){0.f, 0.f, 0.f, 0.f};
#pragma unroll
    for (int ks = 0; ks < 4; ks++) {
        bf16x8 pa[2], vb[6];
#pragma unroll
        for (int mi2 = 0; mi2 < 2; mi2++)
            pa[mi2] = *(const bf16x8*)(sP + (size_t)(wm2 + mi2 * 16 + cl) * 136 + ks * 32 + quad * 8);
#pragma unroll
        for (int ni2 = 0; ni2 < 6; ni2++)
            vb[ni2] = *(const bf16x8*)(sVt + (size_t)(ni2 * 16 + cl) * 136 + ks * 32 + quad * 8);
#pragma unroll
        for (int mi2 = 0; mi2 < 2; mi2++)
#pragma unroll
            for (int ni2 = 0; ni2 < 6; ni2++)
                acc2[mi2][ni2] = __builtin_amdgcn_mfma_f32_16x16x32_bf16(
                    pa[mi2], vb[ni2], acc2[mi2][ni2], 0, 0, 0);
    }
#pragma unroll
    for (int mi2 = 0; mi2 < 2; mi2++) {
#pragma unroll
        for (int r = 0; r < 4; r++) {
            int row = wm2 + mi2 * 16 + quad * 4 + r;
            float iv = sInv[row];
#pragma unroll
            for (int ni2 = 0; ni2 < 6; ni2++) {
                int d = ni2 * 16 + cl;
                attout[rbase + (size_t)row * TDIM + d] =
                    f2b(acc2[mi2][ni2][r] * iv);
            }
        }
    }
}

extern "C" void kernel_launch(void* const* d_in, const int* in_sizes, int n_in,
                              void* d_out, int out_size, void* d_ws, size_t ws_size,
                              hipStream_t stream)
{
    const float* q     = (const float*)d_in[0];
    const float* k     = (const float*)d_in[1];
    const float* v     = (const float*)d_in[2];
    const float* ln1_g = (const float*)d_in[3];
    const float* ln1_b = (const float*)d_in[4];
    const float* wq    = (const float*)d_in[5];
    const float* wk    = (const float*)d_in[6];
    const float* wv    = (const float*)d_in[7];
    const float* wo    = (const float*)d_in[8];
    const float* wo_b  = (const float*)d_in[9];
    const float* ln2_g = (const float*)d_in[10];
    const float* ln2_b = (const float*)d_in[11];
    const float* w1    = (const float*)d_in[12];
    const float* b1    = (const float*)d_in[13];
    const float* w2    = (const float*)d_in[14];
    const float* b2    = (const float*)d_in[15];

    float* out0 = (float*)d_out;
    const size_t S = (size_t)NROWS * TDIM;  // 12,582,912
    float* att = out0 + S;                  // output 1: (2,64,8,128,128) fp32
    unsigned short* ws = (unsigned short*)d_ws;
    if (ws_size < 7 * S * sizeof(unsigned short)) return;  // need ~168 MB

    const size_t W = (size_t)TDIM * TDIM;   // 589,824
    const size_t W2 = (size_t)TDIM * THID;  // 2,359,296

    unsigned short* qn     = ws;          // slot0; later ln2y
    unsigned short* kn     = ws + S;      // slot1; later attout, then w1T/w2T
    unsigned short* vn     = ws + 2 * S;  // slot2; later y
    unsigned short* qh     = ws + 3 * S;  // slot3..5: qh/kh/vh; later hbuf (3..6)
    unsigned short* wqkvoT = ws + 6 * S;  // slot6: wq/wk/wv/wo ^T bf16 (dead at ffn1)
    unsigned short* attout = ws + S;
    unsigned short* y      = ws + 2 * S;
    unsigned short* ln2y   = ws;
    unsigned short* w1T    = ws + S;      // [3072][768], after attout dead
    unsigned short* w2T    = ws + S + W2; // [768][3072]
    unsigned short* hbuf   = ws + 3 * S;  // 16384 x 3072 (4S)

    dim3 blk(256);
    cvt_t_kernel<<<dim3(24, 24), blk, 0, stream>>>(wq, wqkvoT + 0 * W, TDIM, TDIM);
    cvt_t_kernel<<<dim3(24, 24), blk, 0, stream>>>(wk, wqkvoT + 1 * W, TDIM, TDIM);
    cvt_t_kernel<<<dim3(24, 24), blk, 0, stream>>>(wv, wqkvoT + 2 * W, TDIM, TDIM);
    cvt_t_kernel<<<dim3(24, 24), blk, 0, stream>>>(wo, wqkvoT + 3 * W, TDIM, TDIM);
    ln_kernel<true><<<dim3(NROWS, 3), blk, 0, stream>>>(
        q, k, v, ln1_g, ln1_b, qn, kn, vn);
    gemm_kernel<false, false, false, false><<<dim3(6, 128, 3), blk, 0, stream>>>(
        qn, wqkvoT, nullptr, nullptr, qh, NROWS, TDIM, TDIM, S, W, S);
    attn_fused_kernel<<<dim3(1024), blk, 0, stream>>>(qh, qh + S, qh + 2 * S, att, attout);
    gemm_kernel<true, true, false, false><<<dim3(6, 128), blk, 0, stream>>>(
        attout, wqkvoT + 3 * W, wo_b, qn, y, NROWS, TDIM, TDIM, 0, 0, 0);
    cvt_t_kernel<<<dim3(96, 24), blk, 0, stream>>>(w1, w1T, TDIM, THID);
    cvt_t_kernel<<<dim3(24, 96), blk, 0, stream>>>(w2, w2T, THID, TDIM);
    ln_kernel<false><<<dim3(NROWS, 1), blk, 0, stream>>>(
        y, y, y, ln2_g, ln2_b, ln2y, ln2y, ln2y);
    // FFN1 on the 256x256 pipelined kernel (grid 12x64 = 768 blocks, full fill)
    gemm256_kernel<true, true><<<dim3(12, 64), dim3(512), 0, stream>>>(
        ln2y, w1T, b1, hbuf, THID, TDIM);
    gemm_kernel<true, true, false, true><<<dim3(6, 128), blk, 0, stream>>>(
        hbuf, w2T, b2, y, out0, NROWS, TDIM, THID, 0, 0, 0);
}

// Round 5
// 678.374 us; speedup vs baseline: 1.1314x; 1.0192x over previous
//
#include <hip/hip_runtime.h>

// Transformer block. fp32 in/out, bf16 MFMA internal, fp32 accumulation.
// DIM=768 HID=3072 HEADS=8 DEPTH=96 SEQ=128 GROUPS(B*F)=128 ROWS=16384
// R4: fused MFMA attention. R5: XCD swizzle + merged QKV. R6: epilogue de-VALU.
// R7: gemm256 (256x256, 8 waves, counted vmcnt, T2 swizzle) for FFN1.
// R9: gemm256 -> phase-split schedule (m201-style T3+T4+T5): 4 LDS K-tile slots
//     (quad-buffer, 128 KiB), 2 phases/K-tile each {ds_read || 2 global_load_lds
//     || s_barrier || lgkmcnt(0) || setprio MFMA x16 || s_barrier}; one
//     vmcnt(4) per tile with a full-tile issue-to-wait distance (2-tile-deep
//     prefetch). Evidence: R7 counters MfmaUtil 26 / VALU 30 / HBM 18 /
//     conflicts 0 -> serialization-bound monolithic phase; catalog T3 gate.

#define NROWS 16384
#define TDIM 768
#define THID 3072
#define EPS 1e-5f

typedef short bf16x8 __attribute__((ext_vector_type(8)));
typedef float f32x4 __attribute__((ext_vector_type(4)));

__device__ __forceinline__ float b2f(unsigned short u) {
    union { unsigned int i; float f; } v; v.i = ((unsigned int)u) << 16; return v.f;
}
__device__ __forceinline__ unsigned short f2b(float f) {
    union { float f; unsigned int i; } v; v.f = f;
    unsigned int r = v.i + 0x7fffu + ((v.i >> 16) & 1u);
    return (unsigned short)(r >> 16);
}

// async 16B global -> LDS (lds dest is wave-uniform base; HW adds lane*16)
__device__ __forceinline__ void async_copy16(const unsigned short* g, unsigned short* l) {
    __builtin_amdgcn_global_load_lds(
        (const __attribute__((address_space(1))) unsigned int*)g,
        (__attribute__((address_space(3))) unsigned int*)l,
        16, 0, 0);
}

// ---------------- fp32 [K][N] -> bf16 transposed [N][K]
__global__ __launch_bounds__(256) void cvt_t_kernel(
    const float* __restrict__ src, unsigned short* __restrict__ dst, int K, int N)
{
    __shared__ unsigned short tile[32][33];
    int n0 = blockIdx.x * 32, k0 = blockIdx.y * 32;
    int tx = threadIdx.x & 31, ty = threadIdx.x >> 5;
#pragma unroll
    for (int r = ty; r < 32; r += 8)
        tile[r][tx] = f2b(src[(size_t)(k0 + r) * N + n0 + tx]);
    __syncthreads();
#pragma unroll
    for (int r = ty; r < 32; r += 8)
        dst[(size_t)(n0 + r) * K + k0 + tx] = tile[tx][r];
}

// ---------------- LayerNorm: one block per row, up to 3 tensors via blockIdx.y
template<bool IN_F32>
__global__ __launch_bounds__(256) void ln_kernel(
    const void* __restrict__ x0, const void* __restrict__ x1,
    const void* __restrict__ x2,
    const float* __restrict__ g, const float* __restrict__ bb,
    unsigned short* __restrict__ o0, unsigned short* __restrict__ o1,
    unsigned short* __restrict__ o2)
{
    int t = blockIdx.y;
    const void* x = (t == 0) ? x0 : (t == 1) ? x1 : x2;
    unsigned short* o = (t == 0) ? o0 : (t == 1) ? o1 : o2;
    size_t base = (size_t)blockIdx.x * TDIM;
    int tid = threadIdx.x;
    float v[3]; float sum = 0.f, sq = 0.f;
#pragma unroll
    for (int i = 0; i < 3; i++) {
        if constexpr (IN_F32) v[i] = ((const float*)x)[base + tid + i * 256];
        else v[i] = b2f(((const unsigned short*)x)[base + tid + i * 256]);
        sum += v[i]; sq += v[i] * v[i];
    }
#pragma unroll
    for (int o_ = 32; o_ > 0; o_ >>= 1) {
        sum += __shfl_down(sum, o_); sq += __shfl_down(sq, o_);
    }
    __shared__ float s1[4], s2[4];
    __shared__ float smu, srs;
    int wave = tid >> 6, lane = tid & 63;
    if (lane == 0) { s1[wave] = sum; s2[wave] = sq; }
    __syncthreads();
    if (tid == 0) {
        float S = s1[0] + s1[1] + s1[2] + s1[3];
        float Q = s2[0] + s2[1] + s2[2] + s2[3];
        float mu = S / (float)TDIM;
        float var = Q / (float)TDIM - mu * mu;
        smu = mu; srs = rsqrtf(var + EPS);
    }
    __syncthreads();
    float mu = smu, rs = srs;
#pragma unroll
    for (int i = 0; i < 3; i++) {
        int c = tid + i * 256;
        o[base + c] = f2b((v[i] - mu) * rs * g[c] + bb[c]);
    }
}

// ---------------- MFMA GEMM (128x128 tile): C = op(A @ BT^T (+bias)(+gelu)(+res))
template<bool BIAS, bool RES, bool GELU, bool OUTF32>
__global__ __launch_bounds__(256) void gemm_kernel(
    const unsigned short* __restrict__ A, const unsigned short* __restrict__ BT,
    const float* __restrict__ bias, const unsigned short* __restrict__ resid,
    void* __restrict__ Cv, int M, int N, int K,
    size_t aStride, size_t bStride, size_t cStride)
{
    __shared__ unsigned short sA[128][32];
    __shared__ unsigned short sB[128][32];
    int tid = threadIdx.x;

    int nbx = gridDim.x;
    int nwg = nbx * gridDim.y;
    int bid = blockIdx.y * nbx + blockIdx.x;
    int xcd = bid & 7, loc = bid >> 3;
    int qc = nwg >> 3, rc = nwg & 7;
    int swz = (xcd < rc ? xcd * (qc + 1) : rc * (qc + 1) + (xcd - rc) * qc) + loc;
    int row0 = (swz / nbx) * 128;
    int col0 = (swz % nbx) * 128;

    int z = blockIdx.z;
    A  += (size_t)z * aStride;
    BT += (size_t)z * bStride;
    size_t zoff = (size_t)z * cStride;

    int wave = tid >> 6, lane = tid & 63;
    int wm = (wave >> 1) * 64, wn = (wave & 1) * 64;
    int cl = lane & 15, quad = lane >> 4;

    f32x4 acc[4][4];
#pragma unroll
    for (int i = 0; i < 4; i++)
#pragma unroll
        for (int j = 0; j < 4; j++) acc[i][j] = (f32x4){0.f, 0.f, 0.f, 0.f};

    const unsigned short* Arow = A + (size_t)row0 * K;
    const unsigned short* Brow = BT + (size_t)col0 * K;

    int c0 = wave * 128 + lane, c1 = c0 + 64;
    const unsigned short* aS0 = Arow + (size_t)(c0 >> 2) * K + ((c0 & 3) << 3);
    const unsigned short* aS1 = Arow + (size_t)(c1 >> 2) * K + ((c1 & 3) << 3);
    const unsigned short* bS0 = Brow + (size_t)(c0 >> 2) * K + ((c0 & 3) << 3);
    const unsigned short* bS1 = Brow + (size_t)(c1 >> 2) * K + ((c1 & 3) << 3);
    unsigned short* aD0 = &sA[0][0] + (size_t)(wave * 128) * 8;
    unsigned short* aD1 = aD0 + 64 * 8;
    unsigned short* bD0 = &sB[0][0] + (size_t)(wave * 128) * 8;
    unsigned short* bD1 = bD0 + 64 * 8;

    for (int k0 = 0; k0 < K; k0 += 32) {
        async_copy16(aS0 + k0, aD0);
        async_copy16(aS1 + k0, aD1);
        async_copy16(bS0 + k0, bD0);
        async_copy16(bS1 + k0, bD1);
        __syncthreads();
        bf16x8 af[4], bfr[4];
#pragma unroll
        for (int mi = 0; mi < 4; mi++)
            af[mi] = *(const bf16x8*)(&sA[wm + mi * 16 + cl][quad * 8]);
#pragma unroll
        for (int ni = 0; ni < 4; ni++)
            bfr[ni] = *(const bf16x8*)(&sB[wn + ni * 16 + cl][quad * 8]);
#pragma unroll
        for (int mi = 0; mi < 4; mi++)
#pragma unroll
            for (int ni = 0; ni < 4; ni++)
                acc[mi][ni] = __builtin_amdgcn_mfma_f32_16x16x32_bf16(
                    af[mi], bfr[ni], acc[mi][ni], 0, 0, 0);
        __syncthreads();
    }

    float bvv[4];
#pragma unroll
    for (int ni = 0; ni < 4; ni++) {
        if constexpr (BIAS) bvv[ni] = bias[col0 + wn + ni * 16 + cl];
        else bvv[ni] = 0.f;
    }
#pragma unroll
    for (int mi = 0; mi < 4; mi++) {
#pragma unroll
        for (int r = 0; r < 4; r++) {
            int gr = row0 + wm + mi * 16 + quad * 4 + r;
            size_t rb = (size_t)gr * N + col0 + wn + cl;
#pragma unroll
            for (int ni = 0; ni < 4; ni++) {
                float v = acc[mi][ni][r];
                if constexpr (BIAS) v += bvv[ni];
                if constexpr (GELU) {
                    float x = v;
                    float t = x + 0.044715f * x * x * x;
                    float e = __expf(-1.5957691216057308f * t);
                    v = x * __builtin_amdgcn_rcpf(1.0f + e);
                }
                if constexpr (RES) v += b2f(resid[rb + ni * 16]);
                size_t idx = rb + ni * 16 + zoff;
                if constexpr (OUTF32) ((float*)Cv)[idx] = v;
                else ((unsigned short*)Cv)[idx] = f2b(v);
            }
        }
    }
}

// ---------------- MFMA GEMM (256x256 tile, 8 waves, BK=32, quad-buffered,
// phase-split T3+T4+T5). 4 K-tile LDS slots; tile T reads slot T&3 while tile
// T+2 stages into slot (T+2)&3 = (T-2)&3 (last read >=2 barrier-pairs ago).
// Per tile: 2 phases x {ds_read (8/4) | issue 2 gloads | s_barrier | lgkm(0) |
// setprio(1) 16 MFMA setprio(0) | s_barrier}; vmcnt(4) once per tile (full-tile
// issue-to-wait cover). Swizzle: LDS[r][s] = global[r][s ^ ((r>>1)&3)] both
// sides (R7-proven, conflicts = 0).
template<bool BIAS, bool GELU>
__global__ __launch_bounds__(512) void gemm256_kernel(
    const unsigned short* __restrict__ A, const unsigned short* __restrict__ BT,
    const float* __restrict__ bias, unsigned short* __restrict__ C,
    int N, int K)
{
    __shared__ unsigned short lds[4][2][8192];   // [slot][A/B][256*32] = 128 KiB
    int tid = threadIdx.x;

    int nbx = gridDim.x;
    int nwg = nbx * gridDim.y;
    int bid = blockIdx.y * nbx + blockIdx.x;
    int xcd = bid & 7, loc = bid >> 3;
    int qc = nwg >> 3, rc = nwg & 7;
    int swz = (xcd < rc ? xcd * (qc + 1) : rc * (qc + 1) + (xcd - rc) * qc) + loc;
    int row0 = (swz / nbx) * 256;
    int col0 = (swz % nbx) * 256;

    int wave = tid >> 6, lane = tid & 63;
    int wr = wave >> 2, wc = wave & 3;           // 2M x 4N waves
    int cl = lane & 15, quad = lane >> 4;
    int sl8 = (quad ^ ((cl >> 1) & 3)) << 3;     // swizzled 16B slot (elements)

    // staging source: thread t covers LDS-linear slot t (+512); r=t>>2, s=t&3,
    // source col16 pre-swizzled = (t&3) ^ ((t>>3)&3)
    size_t rowoff = (size_t)(tid >> 2) * K + (size_t)(((tid & 3) ^ ((tid >> 3) & 3)) << 3);
    const unsigned short* aS0 = A + (size_t)row0 * K + rowoff;
    const unsigned short* aS1 = aS0 + (size_t)128 * K;
    const unsigned short* bS0 = BT + (size_t)col0 * K + rowoff;
    const unsigned short* bS1 = bS0 + (size_t)128 * K;
    int d0 = wave * 64 * 8;            // dest elem offset, load j=0 (wave-uniform)
    int d1 = (512 + wave * 64) * 8;    // load j=1

    f32x4 acc[8][4];
#pragma unroll
    for (int i = 0; i < 8; i++)
#pragma unroll
        for (int j = 0; j < 4; j++) acc[i][j] = (f32x4){0.f, 0.f, 0.f, 0.f};

    int NT = K >> 5;   // 24 K-tiles
    // prologue: stage tiles 0 (slot 0) and 1 (slot 1)
    async_copy16(aS0, &lds[0][0][d0]);
    async_copy16(bS0, &lds[0][1][d0]);
    async_copy16(aS1, &lds[0][0][d1]);
    async_copy16(bS1, &lds[0][1][d1]);
    async_copy16(aS0 + 32, &lds[1][0][d0]);
    async_copy16(bS0 + 32, &lds[1][1][d0]);
    async_copy16(aS1 + 32, &lds[1][0][d1]);
    async_copy16(bS1 + 32, &lds[1][1][d1]);
    asm volatile("s_waitcnt vmcnt(4)" ::: "memory");   // tile 0 landed; tile 1 in flight
    __builtin_amdgcn_s_barrier();

    for (int T = 0; T < NT; ++T) {
        const unsigned short* pA = &lds[T & 3][0][0];
        const unsigned short* pB = &lds[T & 3][1][0];
        bool pre = (T + 2) < NT;
        int sp = (T + 2) & 3;
        int ko = (T + 2) << 5;
        bf16x8 bfr[4], af[4];
        // ---- phase 0: mi 0..3 (+ all B frags, reused in phase 1)
#pragma unroll
        for (int ni = 0; ni < 4; ni++)
            bfr[ni] = *(const bf16x8*)(pB + (wc * 64 + ni * 16 + cl) * 32 + sl8);
#pragma unroll
        for (int mi = 0; mi < 4; mi++)
            af[mi] = *(const bf16x8*)(pA + (wr * 128 + mi * 16 + cl) * 32 + sl8);
        if (pre) {
            async_copy16(aS0 + ko, &lds[sp][0][d0]);
            async_copy16(bS0 + ko, &lds[sp][1][d0]);
        }
        __builtin_amdgcn_s_barrier();
        asm volatile("s_waitcnt lgkmcnt(0)" ::: "memory");
        __builtin_amdgcn_sched_barrier(0);
        __builtin_amdgcn_s_setprio(1);
#pragma unroll
        for (int mi = 0; mi < 4; mi++)
#pragma unroll
            for (int ni = 0; ni < 4; ni++)
                acc[mi][ni] = __builtin_amdgcn_mfma_f32_16x16x32_bf16(
                    af[mi], bfr[ni], acc[mi][ni], 0, 0, 0);
        __builtin_amdgcn_s_setprio(0);
        __builtin_amdgcn_sched_barrier(0);
        __builtin_amdgcn_s_barrier();
        // ---- phase 1: mi 4..7 (B reused)
#pragma unroll
        for (int mi = 0; mi < 4; mi++)
            af[mi] = *(const bf16x8*)(pA + (wr * 128 + 64 + mi * 16 + cl) * 32 + sl8);
        if (pre) {
            async_copy16(aS1 + ko, &lds[sp][0][d1]);
            async_copy16(bS1 + ko, &lds[sp][1][d1]);
            asm volatile("s_waitcnt vmcnt(4)" ::: "memory");  // tile T+1 landed
        } else {
            asm volatile("s_waitcnt vmcnt(0)" ::: "memory");
        }
        __builtin_amdgcn_s_barrier();
        asm volatile("s_waitcnt lgkmcnt(0)" ::: "memory");
        __builtin_amdgcn_sched_barrier(0);
        __builtin_amdgcn_s_setprio(1);
#pragma unroll
        for (int mi = 0; mi < 4; mi++)
#pragma unroll
            for (int ni = 0; ni < 4; ni++)
                acc[mi + 4][ni] = __builtin_amdgcn_mfma_f32_16x16x32_bf16(
                    af[mi], bfr[ni], acc[mi + 4][ni], 0, 0, 0);
        __builtin_amdgcn_s_setprio(0);
        __builtin_amdgcn_sched_barrier(0);
        __builtin_amdgcn_s_barrier();
    }

    float bvv[4];
#pragma unroll
    for (int ni = 0; ni < 4; ni++) {
        if constexpr (BIAS) bvv[ni] = bias[col0 + wc * 64 + ni * 16 + cl];
        else bvv[ni] = 0.f;
    }
#pragma unroll
    for (int mi = 0; mi < 8; mi++) {
#pragma unroll
        for (int r = 0; r < 4; r++) {
            int gr = row0 + wr * 128 + mi * 16 + quad * 4 + r;
            size_t rb = (size_t)gr * N + col0 + wc * 64 + cl;
#pragma unroll
            for (int ni = 0; ni < 4; ni++) {
                float v = acc[mi][ni][r] + bvv[ni];
                if constexpr (GELU) {
                    float x = v;
                    float tt = x + 0.044715f * x * x * x;
                    float e = __expf(-1.5957691216057308f * tt);
                    v = x * __builtin_amdgcn_rcpf(1.0f + e);
                }
                C[rb + ni * 16] = f2b(v);
            }
        }
    }
}

// ---------------- Fused attention: per-head QK^T -> softmax -> att + PV
__global__ __launch_bounds__(256) void attn_fused_kernel(
    const unsigned short* __restrict__ qh, const unsigned short* __restrict__ kh,
    const unsigned short* __restrict__ vh, float* __restrict__ att,
    unsigned short* __restrict__ attout)
{
    __shared__ __align__(16) unsigned short smem[30464];
    __shared__ float wmax[2][128];
    __shared__ float wsum[2][128];
    __shared__ float sInv[128];
    unsigned short* sQ = smem;
    unsigned short* sK = smem + 12288;
    unsigned short* sP = smem;
    unsigned short* sVt = smem + 17408;

    int hb = blockIdx.x, g = hb >> 3, h = hb & 7;
    int tid = threadIdx.x;
    int wave = tid >> 6, lane = tid & 63;
    int cl = lane & 15, quad = lane >> 4;
    int wm = (wave >> 1) * 64, wn = (wave & 1) * 64;

    size_t rbase = (size_t)g * 128 * TDIM + (size_t)h * 96;

#pragma unroll
    for (int it = 0; it < 6; it++) {
        int cb = wave * 384 + it * 64;
        int c = cb + lane;
        int r = c / 12, dc = (c % 12) * 8;
        async_copy16(qh + rbase + (size_t)r * TDIM + dc, sQ + (size_t)cb * 8);
        async_copy16(kh + rbase + (size_t)r * TDIM + dc, sK + (size_t)cb * 8);
    }
    __syncthreads();

    f32x4 acc[4][4];
#pragma unroll
    for (int i = 0; i < 4; i++)
#pragma unroll
        for (int j = 0; j < 4; j++) acc[i][j] = (f32x4){0.f, 0.f, 0.f, 0.f};
#pragma unroll
    for (int kk = 0; kk < 3; kk++) {
        bf16x8 af[4], bfr[4];
#pragma unroll
        for (int mi = 0; mi < 4; mi++)
            af[mi] = *(const bf16x8*)(sQ + (size_t)(wm + mi * 16 + cl) * 96 + kk * 32 + quad * 8);
#pragma unroll
        for (int ni = 0; ni < 4; ni++)
            bfr[ni] = *(const bf16x8*)(sK + (size_t)(wn + ni * 16 + cl) * 96 + kk * 32 + quad * 8);
#pragma unroll
        for (int mi = 0; mi < 4; mi++)
#pragma unroll
            for (int ni = 0; ni < 4; ni++)
                acc[mi][ni] = __builtin_amdgcn_mfma_f32_16x16x32_bf16(
                    af[mi], bfr[ni], acc[mi][ni], 0, 0, 0);
    }

    const float scale = 0.10206207261596575f;  // 96^-0.5
#pragma unroll
    for (int mi = 0; mi < 4; mi++)
#pragma unroll
        for (int ni = 0; ni < 4; ni++)
#pragma unroll
            for (int r = 0; r < 4; r++) acc[mi][ni][r] *= scale;
#pragma unroll
    for (int mi = 0; mi < 4; mi++) {
#pragma unroll
        for (int r = 0; r < 4; r++) {
            float m = fmaxf(fmaxf(acc[mi][0][r], acc[mi][1][r]),
                            fmaxf(acc[mi][2][r], acc[mi][3][r]));
            m = fmaxf(m, __shfl_xor(m, 1));
            m = fmaxf(m, __shfl_xor(m, 2));
            m = fmaxf(m, __shfl_xor(m, 4));
            m = fmaxf(m, __shfl_xor(m, 8));
            if (cl == 0) wmax[wn >> 6][wm + mi * 16 + quad * 4 + r] = m;
        }
    }
    __syncthreads();

    for (int c = tid; c < 1536; c += 256) {
        int kk2 = c / 12, dc2 = (c % 12) * 8;
        uint4 t_ = *(const uint4*)(vh + rbase + (size_t)kk2 * TDIM + dc2);
        unsigned short* tp = (unsigned short*)&t_;
#pragma unroll
        for (int j = 0; j < 8; j++) {
            int jj = (j + tid) & 7;
            sVt[(size_t)(dc2 + jj) * 136 + kk2] = tp[jj];
        }
    }

#pragma unroll
    for (int mi = 0; mi < 4; mi++) {
#pragma unroll
        for (int r = 0; r < 4; r++) {
            int row = wm + mi * 16 + quad * 4 + r;
            float rm = fmaxf(wmax[0][row], wmax[1][row]);
            float s = 0.f;
#pragma unroll
            for (int ni = 0; ni < 4; ni++) {
                float e = __expf(acc[mi][ni][r] - rm);
                acc[mi][ni][r] = e;
                s += e;
            }
            s += __shfl_xor(s, 1);
            s += __shfl_xor(s, 2);
            s += __shfl_xor(s, 4);
            s += __shfl_xor(s, 8);
            if (cl == 0) wsum[wn >> 6][row] = s;
#pragma unroll
            for (int ni = 0; ni < 4; ni++)
                sP[(size_t)row * 136 + wn + ni * 16 + cl] = f2b(acc[mi][ni][r]);
        }
    }
    __syncthreads();

    if (tid < 128) sInv[tid] = 1.0f / (wsum[0][tid] + wsum[1][tid]);
    __syncthreads();

    size_t pbase = (size_t)hb * 128 * 128;
#pragma unroll
    for (int mi = 0; mi < 4; mi++) {
#pragma unroll
        for (int r = 0; r < 4; r++) {
            int row = wm + mi * 16 + quad * 4 + r;
            float iv = sInv[row];
#pragma unroll
            for (int ni = 0; ni < 4; ni++)
                att[pbase + (size_t)row * 128 + wn + ni * 16 + cl] =
                    acc[mi][ni][r] * iv;
        }
    }

    int wm2 = wave * 32;
    f32x4 acc2[2][6];
#pragma unroll
    for (int i = 0; i < 2; i++)
#pragma unroll
        for (int j = 0; j < 6; j++) acc2[i][j] = (f32x4){0.f, 0.f, 0.f, 0.f};
#pragma unroll
    for (int ks = 0; ks < 4; ks++) {
        bf16x8 pa[2], vb[6];
#pragma unroll
        for (int mi2 = 0; mi2 < 2; mi2++)
            pa[mi2] = *(const bf16x8*)(sP + (size_t)(wm2 + mi2 * 16 + cl) * 136 + ks * 32 + quad * 8);
#pragma unroll
        for (int ni2 = 0; ni2 < 6; ni2++)
            vb[ni2] = *(const bf16x8*)(sVt + (size_t)(ni2 * 16 + cl) * 136 + ks * 32 + quad * 8);
#pragma unroll
        for (int mi2 = 0; mi2 < 2; mi2++)
#pragma unroll
            for (int ni2 = 0; ni2 < 6; ni2++)
                acc2[mi2][ni2] = __builtin_amdgcn_mfma_f32_16x16x32_bf16(
                    pa[mi2], vb[ni2], acc2[mi2][ni2], 0, 0, 0);
    }
#pragma unroll
    for (int mi2 = 0; mi2 < 2; mi2++) {
#pragma unroll
        for (int r = 0; r < 4; r++) {
            int row = wm2 + mi2 * 16 + quad * 4 + r;
            float iv = sInv[row];
#pragma unroll
            for (int ni2 = 0; ni2 < 6; ni2++) {
                int d = ni2 * 16 + cl;
                attout[rbase + (size_t)row * TDIM + d] =
                    f2b(acc2[mi2][ni2][r] * iv);
            }
        }
    }
}

extern "C" void kernel_launch(void* const* d_in, const int* in_sizes, int n_in,
                              void* d_out, int out_size, void* d_ws, size_t ws_size,
                              hipStream_t stream)
{
    const float* q     = (const float*)d_in[0];
    const float* k     = (const float*)d_in[1];
    const float* v     = (const float*)d_in[2];
    const float* ln1_g = (const float*)d_in[3];
    const float* ln1_b = (const float*)d_in[4];
    const float* wq    = (const float*)d_in[5];
    const float* wk    = (const float*)d_in[6];
    const float* wv    = (const float*)d_in[7];
    const float* wo    = (const float*)d_in[8];
    const float* wo_b  = (const float*)d_in[9];
    const float* ln2_g = (const float*)d_in[10];
    const float* ln2_b = (const float*)d_in[11];
    const float* w1    = (const float*)d_in[12];
    const float* b1    = (const float*)d_in[13];
    const float* w2    = (const float*)d_in[14];
    const float* b2    = (const float*)d_in[15];

    float* out0 = (float*)d_out;
    const size_t S = (size_t)NROWS * TDIM;  // 12,582,912
    float* att = out0 + S;                  // output 1: (2,64,8,128,128) fp32
    unsigned short* ws = (unsigned short*)d_ws;
    if (ws_size < 7 * S * sizeof(unsigned short)) return;  // need ~168 MB

    const size_t W = (size_t)TDIM * TDIM;   // 589,824
    const size_t W2 = (size_t)TDIM * THID;  // 2,359,296

    unsigned short* qn     = ws;          // slot0; later ln2y
    unsigned short* kn     = ws + S;      // slot1; later attout, then w1T/w2T
    unsigned short* vn     = ws + 2 * S;  // slot2; later y
    unsigned short* qh     = ws + 3 * S;  // slot3..5: qh/kh/vh; later hbuf (3..6)
    unsigned short* wqkvoT = ws + 6 * S;  // slot6: wq/wk/wv/wo ^T bf16 (dead at ffn1)
    unsigned short* attout = ws + S;
    unsigned short* y      = ws + 2 * S;
    unsigned short* ln2y   = ws;
    unsigned short* w1T    = ws + S;      // [3072][768], after attout dead
    unsigned short* w2T    = ws + S + W2; // [768][3072]
    unsigned short* hbuf   = ws + 3 * S;  // 16384 x 3072 (4S)

    dim3 blk(256);
    cvt_t_kernel<<<dim3(24, 24), blk, 0, stream>>>(wq, wqkvoT + 0 * W, TDIM, TDIM);
    cvt_t_kernel<<<dim3(24, 24), blk, 0, stream>>>(wk, wqkvoT + 1 * W, TDIM, TDIM);
    cvt_t_kernel<<<dim3(24, 24), blk, 0, stream>>>(wv, wqkvoT + 2 * W, TDIM, TDIM);
    cvt_t_kernel<<<dim3(24, 24), blk, 0, stream>>>(wo, wqkvoT + 3 * W, TDIM, TDIM);
    ln_kernel<true><<<dim3(NROWS, 3), blk, 0, stream>>>(
        q, k, v, ln1_g, ln1_b, qn, kn, vn);
    gemm_kernel<false, false, false, false><<<dim3(6, 128, 3), blk, 0, stream>>>(
        qn, wqkvoT, nullptr, nullptr, qh, NROWS, TDIM, TDIM, S, W, S);
    attn_fused_kernel<<<dim3(1024), blk, 0, stream>>>(qh, qh + S, qh + 2 * S, att, attout);
    gemm_kernel<true, true, false, false><<<dim3(6, 128), blk, 0, stream>>>(
        attout, wqkvoT + 3 * W, wo_b, qn, y, NROWS, TDIM, TDIM, 0, 0, 0);
    cvt_t_kernel<<<dim3(96, 24), blk, 0, stream>>>(w1, w1T, TDIM, THID);
    cvt_t_kernel<<<dim3(24, 96), blk, 0, stream>>>(w2, w2T, THID, TDIM);
    ln_kernel<false><<<dim3(NROWS, 1), blk, 0, stream>>>(
        y, y, y, ln2_g, ln2_b, ln2y, ln2y, ln2y);
    // FFN1 on the 256x256 phase-split kernel (grid 12x64 = 768 blocks)
    gemm256_kernel<true, true><<<dim3(12, 64), dim3(512), 0, stream>>>(
        ln2y, w1T, b1, hbuf, THID, TDIM);
    gemm_kernel<true, true, false, true><<<dim3(6, 128), blk, 0, stream>>>(
        hbuf, w2T, b2, y, out0, NROWS, TDIM, THID, 0, 0, 0);
}